// Round 11
// baseline (1083.994 us; speedup 1.0000x reference)
//
#include <hip/hip_runtime.h>
#include <math.h>

#define NN 50000
#define EE 500000
#define DD 128
#define KK 5
#define LL 2

// 4-panel layout for f16 N x D state: [4 panels][NN][32] (panel p = cols 32p..32p+31)
#define PSZ32 ((size_t)NN * 32)

typedef _Float16 f16x8 __attribute__((ext_vector_type(8)));
typedef float f32x4 __attribute__((ext_vector_type(4)));
typedef unsigned int u32x4 __attribute__((ext_vector_type(4)));

__device__ __forceinline__ ushort f2h(float x) {
    union { _Float16 h; ushort u; } v; v.h = (_Float16)x; return v.u;
}

// ===================== graph preprocessing =====================

__global__ __launch_bounds__(256) void edge_pass1(
    const int* __restrict__ src, const int* __restrict__ dst,
    const float* __restrict__ ew,
    float* __restrict__ deg, int* __restrict__ hist)
{
    int e = blockIdx.x * blockDim.x + threadIdx.x;
    if (e >= EE) return;
    atomicAdd(&deg[src[e]], ew[e]);
    atomicAdd(&hist[dst[e]], 1);
}

__global__ __launch_bounds__(256) void dinv_kernel(
    const float* __restrict__ deg, float* __restrict__ dinv)
{
    int i = blockIdx.x * blockDim.x + threadIdx.x;
    if (i >= NN) return;
    float d = deg[i];
    dinv[i] = (d > 0.f) ? (1.f / sqrtf(d)) : 0.f;
}

// register-chunked single-block scan
#define SCAN_C ((NN + 1023) / 1024)
__global__ __launch_bounds__(1024) void scan_kernel(
    const int* __restrict__ hist, int* __restrict__ row_ptr)
{
    __shared__ int sums[1024];
    const int t = threadIdx.x;
    const int base = t * SCAN_C;
    int local[SCAN_C];
    int s = 0;
#pragma unroll
    for (int j = 0; j < SCAN_C; ++j) {
        int i = base + j;
        int v = (i < NN) ? hist[i] : 0;
        s += v;
        local[j] = s;
    }
    sums[t] = s;
    __syncthreads();
    for (int off = 1; off < 1024; off <<= 1) {
        int v = (t >= off) ? sums[t - off] : 0;
        __syncthreads();
        sums[t] += v;
        __syncthreads();
    }
    int excl = sums[t] - s;
    if (t == 0) row_ptr[0] = 0;
#pragma unroll
    for (int j = 0; j < SCAN_C; ++j) {
        int i = base + j;
        if (i < NN) row_ptr[i + 1] = excl + local[j];
    }
}

__global__ __launch_bounds__(256) void copy_fill(
    const int* __restrict__ row_ptr, int* __restrict__ fill)
{
    int i = blockIdx.x * blockDim.x + threadIdx.x;
    if (i < NN) fill[i] = row_ptr[i];
}

__global__ __launch_bounds__(256) void edge_scatter(
    const int* __restrict__ src, const int* __restrict__ dst,
    const float* __restrict__ ew, const float* __restrict__ dinv,
    int* __restrict__ fill,
    int* __restrict__ src_srt, float* __restrict__ w_srt)
{
    int e = blockIdx.x * blockDim.x + threadIdx.x;
    if (e >= EE) return;
    int s = src[e], t = dst[e];
    float w = -dinv[s] * ew[e] * dinv[t];
    int pos = atomicAdd(&fill[t], 1);
    src_srt[pos] = s;
    w_srt[pos] = w;
}

// ===================== scalar Chebyshev vectors (for H = ones) =====================
__global__ __launch_bounds__(256) void propv_kernel(
    const int* __restrict__ rp, const int* __restrict__ ss, const float* __restrict__ sw,
    const float* __restrict__ tin, const float* __restrict__ tprev, float* __restrict__ tout,
    float alpha, float beta, int ones_in, int ones_prev)
{
    int i = blockIdx.x * blockDim.x + threadIdx.x;
    if (i >= NN) return;
    float acc = 0.f;
    int e0 = rp[i], e1 = rp[i + 1];
    int e = e0;
    for (; e + 4 <= e1; e += 4) {
        float t0 = ones_in ? 1.f : tin[ss[e]];
        float t1v = ones_in ? 1.f : tin[ss[e + 1]];
        float t2v = ones_in ? 1.f : tin[ss[e + 2]];
        float t3v = ones_in ? 1.f : tin[ss[e + 3]];
        acc += sw[e] * t0 + sw[e + 1] * t1v + sw[e + 2] * t2v + sw[e + 3] * t3v;
    }
    for (; e < e1; ++e) {
        float tv = ones_in ? 1.f : tin[ss[e]];
        acc += sw[e] * tv;
    }
    float pv = ones_prev ? 1.f : (tprev ? tprev[i] : 0.f);
    tout[i] = alpha * acc + beta * pv;
}

// colsum of Wh[l, g(0..1), k] -> scol[(l*2+g)*K + k][d]
__global__ __launch_bounds__(128) void colsum_kernel(
    const float* __restrict__ Wh, float* __restrict__ scol)
{
    int b = blockIdx.x;
    int k = b % KK;
    int g = (b / KK) % 2;
    int l = b / (2 * KK);
    int d = threadIdx.x;
    const float* Wp = Wh + ((size_t)((l * 3 + g) * KK + k)) * DD * DD;
    float s = 0.f;
    for (int r = 0; r < DD; ++r) s += Wp[r * DD + d];
    scol[((size_t)((l * 2 + g) * KK + k)) * DD + d] = s;
}

// ===================== weight convert: fp32 -> f16 fragment-major =============
// per 128x128 tile: B-fragment (ko, fc) is contiguous 1KB:
//   ushort idx = ko*4096 + fc*512 + lr*32 + lk*8 + j
//   holds W^T[dout = fc*16+lr][din = ko*32 + lk*8 + j]
// mode 0: src tile = t (Wx); mode 1: src tile = ((t/K)*3+2)*K + t%K (Wh gate 2)
__global__ __launch_bounds__(256) void wconv_frag(
    const float* __restrict__ W, ushort* __restrict__ out, int mode)
{
    int t = blockIdx.x;
    int st = (mode == 0) ? t : ((t / KK) * 3 + 2) * KK + (t % KK);
    const float* Wp = W + (size_t)st * DD * DD;
    ushort* op = out + (size_t)t * DD * DD;
    for (int idx = threadIdx.x; idx < DD * DD; idx += 256) {
        int j  = idx & 7;
        int lk = (idx >> 3) & 3;
        int lr = (idx >> 5) & 15;
        int fc = (idx >> 9) & 7;
        int ko = idx >> 12;
        int dout = fc * 16 + lr;
        int din  = ko * 32 + lk * 8 + j;
        op[idx] = f2h(Wp[din * DD + dout]);
    }
}

// ===================== f32 (row-major) -> f16 4-panels =====================
__global__ __launch_bounds__(256) void f32_to_f16_panel(
    const float* __restrict__ in, ushort* __restrict__ out, int n8)
{
    int j = blockIdx.x * blockDim.x + threadIdx.x;
    if (j >= n8) return;
    int flat = j * 8;
    int i = flat >> 7;        // node
    int d0 = flat & 127;      // 0,8,...,120
    float4 a = *(const float4*)(in + (size_t)i * DD + d0);
    float4 b = *(const float4*)(in + (size_t)i * DD + d0 + 4);
    f16x8 o;
    o[0] = (_Float16)a.x; o[1] = (_Float16)a.y; o[2] = (_Float16)a.z; o[3] = (_Float16)a.w;
    o[4] = (_Float16)b.x; o[5] = (_Float16)b.y; o[6] = (_Float16)b.z; o[7] = (_Float16)b.w;
    *(f16x8*)(out + (size_t)(d0 >> 5) * PSZ32 + (size_t)i * 32 + (d0 & 31)) = o;
}

// ===================== dense fp16 propagation, 4x32-col panels + NT hints =====
// panel = blockIdx&3 rides round-robin XCD dispatch; streaming traffic (ss, sw,
// output) uses nontemporal hints so the gather-target x-panel stays L2-resident.
__global__ __launch_bounds__(256) void prop_mat(
    const int* __restrict__ rp, const int* __restrict__ ss, const float* __restrict__ sw,
    const ushort* __restrict__ x, const ushort* __restrict__ prev,
    ushort* __restrict__ out, float alpha, float beta)
{
    const int p = blockIdx.x & 3;
    const int node = (blockIdx.x >> 2) * 64 + (threadIdx.x >> 2);
    if (node >= NN) return;
    const int lane8 = (threadIdx.x & 3) * 8;
    const ushort* xp = x + (size_t)p * PSZ32 + lane8;
    float acc[8];
#pragma unroll
    for (int j = 0; j < 8; ++j) acc[j] = 0.f;
    int e0 = rp[node], e1 = rp[node + 1];
    int e = e0;
    for (; e + 8 <= e1; e += 8) {
        int s0 = __builtin_nontemporal_load(ss + e);
        int s1 = __builtin_nontemporal_load(ss + e + 1);
        int s2 = __builtin_nontemporal_load(ss + e + 2);
        int s3 = __builtin_nontemporal_load(ss + e + 3);
        int s4 = __builtin_nontemporal_load(ss + e + 4);
        int s5 = __builtin_nontemporal_load(ss + e + 5);
        int s6 = __builtin_nontemporal_load(ss + e + 6);
        int s7 = __builtin_nontemporal_load(ss + e + 7);
        float w0 = __builtin_nontemporal_load(sw + e);
        float w1 = __builtin_nontemporal_load(sw + e + 1);
        float w2 = __builtin_nontemporal_load(sw + e + 2);
        float w3 = __builtin_nontemporal_load(sw + e + 3);
        float w4 = __builtin_nontemporal_load(sw + e + 4);
        float w5 = __builtin_nontemporal_load(sw + e + 5);
        float w6 = __builtin_nontemporal_load(sw + e + 6);
        float w7 = __builtin_nontemporal_load(sw + e + 7);
        f16x8 r0 = *(const f16x8*)(xp + (size_t)s0 * 32);
        f16x8 r1 = *(const f16x8*)(xp + (size_t)s1 * 32);
        f16x8 r2 = *(const f16x8*)(xp + (size_t)s2 * 32);
        f16x8 r3 = *(const f16x8*)(xp + (size_t)s3 * 32);
        f16x8 r4 = *(const f16x8*)(xp + (size_t)s4 * 32);
        f16x8 r5 = *(const f16x8*)(xp + (size_t)s5 * 32);
        f16x8 r6 = *(const f16x8*)(xp + (size_t)s6 * 32);
        f16x8 r7 = *(const f16x8*)(xp + (size_t)s7 * 32);
#pragma unroll
        for (int j = 0; j < 8; ++j)
            acc[j] += w0 * (float)r0[j] + w1 * (float)r1[j] + w2 * (float)r2[j] + w3 * (float)r3[j]
                    + w4 * (float)r4[j] + w5 * (float)r5[j] + w6 * (float)r6[j] + w7 * (float)r7[j];
    }
    for (; e + 4 <= e1; e += 4) {
        int s0 = ss[e], s1 = ss[e + 1], s2 = ss[e + 2], s3 = ss[e + 3];
        float w0 = sw[e], w1 = sw[e + 1], w2 = sw[e + 2], w3 = sw[e + 3];
        f16x8 r0 = *(const f16x8*)(xp + (size_t)s0 * 32);
        f16x8 r1 = *(const f16x8*)(xp + (size_t)s1 * 32);
        f16x8 r2 = *(const f16x8*)(xp + (size_t)s2 * 32);
        f16x8 r3 = *(const f16x8*)(xp + (size_t)s3 * 32);
#pragma unroll
        for (int j = 0; j < 8; ++j)
            acc[j] += w0 * (float)r0[j] + w1 * (float)r1[j] + w2 * (float)r2[j] + w3 * (float)r3[j];
    }
    for (; e < e1; ++e) {
        int s = ss[e];
        float w = sw[e];
        f16x8 r = *(const f16x8*)(xp + (size_t)s * 32);
#pragma unroll
        for (int j = 0; j < 8; ++j) acc[j] += w * (float)r[j];
    }
    union { f16x8 v; u32x4 u; } o;
    if (beta != 0.f && prev) {
        f16x8 pv = *(const f16x8*)(prev + (size_t)p * PSZ32 + (size_t)node * 32 + lane8);
#pragma unroll
        for (int j = 0; j < 8; ++j) o.v[j] = (_Float16)(alpha * acc[j] + beta * (float)pv[j]);
    } else {
#pragma unroll
        for (int j = 0; j < 8; ++j) o.v[j] = (_Float16)(alpha * acc[j]);
    }
    __builtin_nontemporal_store(o.u, (u32x4*)(out + (size_t)p * PSZ32 + (size_t)node * 32 + lane8));
}

// ===================== MFMA gate core: NO LDS, no barriers ====================
// B fragments read directly from global (fragment-major, L2-resident).
// A fragments from 32-col panels: 64 lanes at fixed ko read 16 consecutive
// node-rows x 64B = fully coalesced.
template<int NFR>
__device__ __forceinline__ void mm_gate(
    const ushort* __restrict__ const* Ts, const ushort* __restrict__ Wg,
    const int* rowg, const bool* ok, int lk, int lr, f32x4 acc[NFR][8])
{
#pragma unroll
    for (int fr = 0; fr < NFR; ++fr)
#pragma unroll
        for (int fc = 0; fc < 8; ++fc) acc[fr][fc] = (f32x4){0.f, 0.f, 0.f, 0.f};
#pragma unroll
    for (int k = 0; k < KK; ++k) {
        f16x8 a[NFR][4];
#pragma unroll
        for (int fr = 0; fr < NFR; ++fr) {
#pragma unroll
            for (int ko = 0; ko < 4; ++ko) {
                const ushort* ap = Ts[k] + (size_t)ko * PSZ32
                                 + (size_t)rowg[fr] * 32 + lk * 8;
                if (ok[fr]) a[fr][ko] = *(const f16x8*)ap;
                else a[fr][ko] = (f16x8){0, 0, 0, 0, 0, 0, 0, 0};
            }
        }
        const char* WB = (const char*)(Wg + (size_t)k * DD * DD);
        const int lo = lr * 64 + lk * 16;
#pragma unroll
        for (int ko = 0; ko < 4; ++ko) {
#pragma unroll
            for (int fc = 0; fc < 8; ++fc) {
                f16x8 b = *(const f16x8*)(WB + ((ko * 8 + fc) << 10) + lo);
#pragma unroll
                for (int fr = 0; fr < NFR; ++fr)
                    acc[fr][fc] = __builtin_amdgcn_mfma_f32_16x16x32_f16(a[fr][ko], b, acc[fr][fc], 0, 0, 0);
            }
        }
    }
}

__device__ __forceinline__ int xcd_swz(int b, int nwg) {
    int xcd = b & 7, idx = b >> 3;
    int q = nwg >> 3, rr = nwg & 7;
    int start = (xcd < rr) ? xcd * (q + 1) : rr * (q + 1) + (xcd - rr) * q;
    return start + idx;
}

// ===================== fp16 MFMA Chebyshev matmul (parallel gates, 128-row) ===
__global__ __launch_bounds__(256) void cheb_mm_mfma(
    const ushort* __restrict__ T0, const ushort* __restrict__ T1,
    const ushort* __restrict__ T2, const ushort* __restrict__ T3,
    const ushort* __restrict__ T4,
    const ushort* __restrict__ Wt, int gate_stride,
    float* __restrict__ outbase, size_t out_stride, int ngates)
{
    const int lin = xcd_swz(blockIdx.x, gridDim.x);
    const int tile = lin / ngates;
    const int g = lin - tile * ngates;

    const int lane = threadIdx.x & 63;
    const int wid = threadIdx.x >> 6;
    const int lr = lane & 15;
    const int lk = lane >> 4;
    const int r0 = tile * 128;
    const ushort* Ts[5] = {T0, T1, T2, T3, T4};

    int rowg[2] = {r0 + wid * 32 + lr, r0 + wid * 32 + lr + 16};
    bool ok[2] = {rowg[0] < NN, rowg[1] < NN};

    f32x4 acc[2][8];
    mm_gate<2>(Ts, Wt + (size_t)g * gate_stride, rowg, ok, lk, lr, acc);

    float* outp = outbase + (size_t)g * out_stride;
#pragma unroll
    for (int fr = 0; fr < 2; ++fr) {
#pragma unroll
        for (int j = 0; j < 4; ++j) {
            int grow = r0 + wid * 32 + fr * 16 + lk * 4 + j;
            if (grow < NN) {
#pragma unroll
                for (int fc = 0; fc < 8; ++fc) {
                    int col = fc * 16 + lr;
                    outp[(size_t)grow * DD + col] = acc[fr][fc][j];
                }
            }
        }
    }
}

// ===================== fused Wh-matmul + final GRU gate (64-row tiles) ========
__global__ __launch_bounds__(256) void cheb_mm_final(
    const ushort* __restrict__ T0, const ushort* __restrict__ T1,
    const ushort* __restrict__ T2, const ushort* __restrict__ T3,
    const ushort* __restrict__ T4,
    const ushort* __restrict__ Wt,
    const float* __restrict__ Xh, const float* __restrict__ Xz,
    const float* __restrict__ bx, const float* __restrict__ bh, int l,
    float* __restrict__ out, ushort* __restrict__ h16, int write_f32)
{
    const int tile = xcd_swz(blockIdx.x, gridDim.x);
    const int lane = threadIdx.x & 63;
    const int wid = threadIdx.x >> 6;
    const int lr = lane & 15;
    const int lk = lane >> 4;
    const int r0 = tile * 64;
    const ushort* Ts[5] = {T0, T1, T2, T3, T4};

    int rowg[1] = {r0 + wid * 16 + lr};
    bool ok[1] = {rowg[0] < NN};

    f32x4 acc[1][8];
    mm_gate<1>(Ts, Wt, rowg, ok, lk, lr, acc);

    const float* b0 = bx + (size_t)(l * 3 + 2) * DD;
    const float* b1 = bh + (size_t)(l * 3 + 2) * DD;
#pragma unroll
    for (int j = 0; j < 4; ++j) {
        int grow = r0 + wid * 16 + lk * 4 + j;
        if (grow < NN) {
#pragma unroll
            for (int fc = 0; fc < 8; ++fc) {
                int d = fc * 16 + lr;
                size_t idx = (size_t)grow * DD + d;
                float pre = acc[0][fc][j] + Xh[idx] + b0[d] + b1[d];
                float ht = tanhf(pre);
                float z = Xz[idx];
                float hn = z + (1.f - z) * ht;
                float h = hn > 0.f ? hn : 0.f;
                if (write_f32) out[idx] = h;
                else h16[(size_t)(d >> 5) * PSZ32 + (size_t)grow * 32 + (d & 31)] = f2h(h);
            }
        }
    }
}

// ===================== gate kernel: Z,R from raw matmul results ===============
__global__ __launch_bounds__(256) void gate_zr_kernel(
    float* __restrict__ Xz, const float* __restrict__ Xr, ushort* __restrict__ Xr_f16,
    const float* __restrict__ tvec, const float* __restrict__ scol,
    const float* __restrict__ bx, const float* __restrict__ bh, int l)
{
    int idx = blockIdx.x * blockDim.x + threadIdx.x;
    if (idx >= NN * DD) return;
    int i = idx >> 7;
    int d = idx & 127;
    float t1 = tvec[i], t2 = tvec[NN + i], t3 = tvec[2 * NN + i], t4 = tvec[3 * NN + i];

    const float* s0 = scol + (size_t)((l * 2 + 0) * KK) * DD;
    float hz = s0[d] + t1 * s0[DD + d] + t2 * s0[2 * DD + d] + t3 * s0[3 * DD + d] + t4 * s0[4 * DD + d];
    float z = Xz[idx] + bx[(l * 3 + 0) * DD + d] + bh[(l * 3 + 0) * DD + d] + hz;
    Xz[idx] = 1.f / (1.f + expf(-z));

    const float* s1 = scol + (size_t)((l * 2 + 1) * KK) * DD;
    float hr = s1[d] + t1 * s1[DD + d] + t2 * s1[2 * DD + d] + t3 * s1[3 * DD + d] + t4 * s1[4 * DD + d];
    float r = Xr[idx] + bx[(l * 3 + 1) * DD + d] + bh[(l * 3 + 1) * DD + d] + hr;
    Xr_f16[(size_t)(d >> 5) * PSZ32 + (size_t)i * 32 + (d & 31)] = f2h(1.f / (1.f + expf(-r)));
}

// ===================== host orchestration =====================

extern "C" void kernel_launch(void* const* d_in, const int* in_sizes, int n_in,
                              void* d_out, int out_size, void* d_ws, size_t ws_size,
                              hipStream_t stream)
{
    const int*   ei  = (const int*)d_in[0];
    const float* ew  = (const float*)d_in[1];
    const float* emb = (const float*)d_in[2];
    const float* Wx  = (const float*)d_in[3];
    const float* bx  = (const float*)d_in[4];
    const float* Wh  = (const float*)d_in[5];
    const float* bh  = (const float*)d_in[6];
    float* out = (float*)d_out;

    const int* src = ei;
    const int* dst = ei + EE;

    char* ws = (char*)d_ws;
    size_t off = 0;
    auto alloc = [&](size_t nbytes) -> char* {
        char* p = ws + off;
        off = (off + nbytes + 255) & ~(size_t)255;
        return p;
    };
    float*  deg     = (float*)alloc((size_t)NN * 4);
    float*  dinv    = (float*)alloc((size_t)NN * 4);
    int*    hist    = (int*)alloc((size_t)(NN + 1) * 4);
    int*    row_ptr = (int*)alloc((size_t)(NN + 1) * 4);
    int*    fill    = (int*)alloc((size_t)(NN + 1) * 4);
    int*    src_srt = (int*)alloc((size_t)EE * 4);
    float*  w_srt   = (float*)alloc((size_t)EE * 4);
    float*  tvec    = (float*)alloc((size_t)4 * NN * 4);
    float*  scol    = (float*)alloc((size_t)LL * 2 * KK * DD * 4);
    float*  X       = (float*)alloc((size_t)3 * NN * DD * 4);    // Xz,Xr,Xh fp32
    ushort* Th      = (ushort*)alloc((size_t)4 * NN * DD * 2);   // T1..T4 f16 panels
    ushort* x_f16   = (ushort*)alloc((size_t)NN * DD * 2);       // panels
    ushort* Xr_f16  = (ushort*)alloc((size_t)NN * DD * 2);       // panels
    ushort* WxT     = (ushort*)alloc((size_t)LL * 3 * KK * DD * DD * 2);
    ushort* WhT2    = (ushort*)alloc((size_t)LL * KK * DD * DD * 2);
    (void)ws_size; (void)in_sizes; (void)n_in; (void)out_size;

    float* Xz = X;
    float* Xr = X + (size_t)NN * DD;
    float* Xh = X + (size_t)2 * NN * DD;
    ushort* T1 = Th;
    ushort* T2 = Th + (size_t)NN * DD;
    ushort* T3 = Th + (size_t)2 * NN * DD;
    ushort* T4 = Th + (size_t)3 * NN * DD;

    const int EG = (EE + 255) / 256;
    const int NG = (NN + 255) / 256;
    const int PG = ((NN + 63) / 64) * 4;       // 4-panel prop grid
    const int ELG = (NN * DD + 255) / 256;
    const int MMG = (NN + 127) / 128;
    const int MMG2 = (NN + 63) / 64;
    const int CVG = (NN * DD / 8 + 255) / 256;
    const int GATE_STRIDE = KK * DD * DD;  // ushorts per gate

    hipMemsetAsync(deg, 0, (size_t)NN * 4, stream);
    hipMemsetAsync(hist, 0, (size_t)(NN + 1) * 4, stream);

    edge_pass1<<<EG, 256, 0, stream>>>(src, dst, ew, deg, hist);
    dinv_kernel<<<NG, 256, 0, stream>>>(deg, dinv);
    scan_kernel<<<1, 1024, 0, stream>>>(hist, row_ptr);
    copy_fill<<<NG, 256, 0, stream>>>(row_ptr, fill);
    edge_scatter<<<EG, 256, 0, stream>>>(src, dst, ew, dinv, fill, src_srt, w_srt);

    // scalar Chebyshev vectors t1..t4 (t0 = ones, implicit)
    float* t1 = tvec;
    float* t2 = tvec + NN;
    float* t3 = tvec + 2 * NN;
    float* t4 = tvec + 3 * NN;
    propv_kernel<<<NG, 256, 0, stream>>>(row_ptr, src_srt, w_srt, nullptr, nullptr, t1, 1.f,  0.f, 1, 0);
    propv_kernel<<<NG, 256, 0, stream>>>(row_ptr, src_srt, w_srt, t1, nullptr,      t2, 2.f, -1.f, 0, 1);
    propv_kernel<<<NG, 256, 0, stream>>>(row_ptr, src_srt, w_srt, t2, t1,           t3, 2.f, -1.f, 0, 0);
    propv_kernel<<<NG, 256, 0, stream>>>(row_ptr, src_srt, w_srt, t3, t2,           t4, 2.f, -1.f, 0, 0);

    colsum_kernel<<<LL * 2 * KK, 128, 0, stream>>>(Wh, scol);

    // weights -> f16 fragment-major (read directly by MFMA from global/L2)
    wconv_frag<<<LL * 3 * KK, 256, 0, stream>>>(Wx, WxT, 0);
    wconv_frag<<<LL * KK, 256, 0, stream>>>(Wh, WhT2, 1);

    // emb -> f16 panels
    f32_to_f16_panel<<<CVG, 256, 0, stream>>>(emb, x_f16, NN * DD / 8);

    for (int l = 0; l < LL; ++l) {
        // Chebyshev basis of x (f16 panels, fp32 accumulate)
        prop_mat<<<PG, 256, 0, stream>>>(row_ptr, src_srt, w_srt, x_f16, nullptr, T1, 1.f,  0.f);
        prop_mat<<<PG, 256, 0, stream>>>(row_ptr, src_srt, w_srt, T1,    x_f16,   T2, 2.f, -1.f);
        prop_mat<<<PG, 256, 0, stream>>>(row_ptr, src_srt, w_srt, T2,    T1,      T3, 2.f, -1.f);
        prop_mat<<<PG, 256, 0, stream>>>(row_ptr, src_srt, w_srt, T3,    T2,      T4, 2.f, -1.f);

        // Xg = sum_k T_k @ Wx[l,g,k], g=0..2 (parallel gate blocks, XCD co-located)
        cheb_mm_mfma<<<MMG * 3, 256, 0, stream>>>(x_f16, T1, T2, T3, T4,
                                             WxT + (size_t)l * 3 * GATE_STRIDE, GATE_STRIDE,
                                             Xz, (size_t)NN * DD, 3);

        // Z, R (rank-K ones-side cheb + biases); Xz sigmoid in-place + Xr f16 panels
        gate_zr_kernel<<<ELG, 256, 0, stream>>>(Xz, Xr, Xr_f16, tvec, scol, bx, bh, l);

        // Chebyshev basis of R (H*R == R since H == ones)
        prop_mat<<<PG, 256, 0, stream>>>(row_ptr, src_srt, w_srt, Xr_f16, nullptr, T1, 1.f,  0.f);
        prop_mat<<<PG, 256, 0, stream>>>(row_ptr, src_srt, w_srt, T1,     Xr_f16,  T2, 2.f, -1.f);
        prop_mat<<<PG, 256, 0, stream>>>(row_ptr, src_srt, w_srt, T2,     T1,      T3, 2.f, -1.f);
        prop_mat<<<PG, 256, 0, stream>>>(row_ptr, src_srt, w_srt, T3,     T2,      T4, 2.f, -1.f);

        // fused: Xh + sum_k TR_k @ Wh[l,2,k] + final GRU gate (64-row tiles)
        cheb_mm_final<<<MMG2, 256, 0, stream>>>(Xr_f16, T1, T2, T3, T4,
                                               WhT2 + (size_t)l * GATE_STRIDE,
                                               Xh, Xz, bx, bh, l,
                                               out, x_f16, (l == LL - 1) ? 1 : 0);
    }
}

// Round 12
// 898.732 us; speedup vs baseline: 1.2061x; 1.2061x over previous
//
#include <hip/hip_runtime.h>
#include <math.h>

#define NN 50000
#define EE 500000
#define DD 128
#define KK 5
#define LL 2

typedef _Float16 f16x8 __attribute__((ext_vector_type(8)));
typedef float f32x4 __attribute__((ext_vector_type(4)));
typedef unsigned int u32x4 __attribute__((ext_vector_type(4)));

__device__ __forceinline__ ushort f2h(float x) {
    union { _Float16 h; ushort u; } v; v.h = (_Float16)x; return v.u;
}

// ===================== graph preprocessing =====================

__global__ __launch_bounds__(256) void edge_pass1(
    const int* __restrict__ src, const int* __restrict__ dst,
    const float* __restrict__ ew,
    float* __restrict__ deg, int* __restrict__ hist)
{
    int e = blockIdx.x * blockDim.x + threadIdx.x;
    if (e >= EE) return;
    atomicAdd(&deg[src[e]], ew[e]);
    atomicAdd(&hist[dst[e]], 1);
}

__global__ __launch_bounds__(256) void dinv_kernel(
    const float* __restrict__ deg, float* __restrict__ dinv)
{
    int i = blockIdx.x * blockDim.x + threadIdx.x;
    if (i >= NN) return;
    float d = deg[i];
    dinv[i] = (d > 0.f) ? (1.f / sqrtf(d)) : 0.f;
}

// register-chunked single-block scan
#define SCAN_C ((NN + 1023) / 1024)
__global__ __launch_bounds__(1024) void scan_kernel(
    const int* __restrict__ hist, int* __restrict__ row_ptr)
{
    __shared__ int sums[1024];
    const int t = threadIdx.x;
    const int base = t * SCAN_C;
    int local[SCAN_C];
    int s = 0;
#pragma unroll
    for (int j = 0; j < SCAN_C; ++j) {
        int i = base + j;
        int v = (i < NN) ? hist[i] : 0;
        s += v;
        local[j] = s;
    }
    sums[t] = s;
    __syncthreads();
    for (int off = 1; off < 1024; off <<= 1) {
        int v = (t >= off) ? sums[t - off] : 0;
        __syncthreads();
        sums[t] += v;
        __syncthreads();
    }
    int excl = sums[t] - s;
    if (t == 0) row_ptr[0] = 0;
#pragma unroll
    for (int j = 0; j < SCAN_C; ++j) {
        int i = base + j;
        if (i < NN) row_ptr[i + 1] = excl + local[j];
    }
}

__global__ __launch_bounds__(256) void copy_fill(
    const int* __restrict__ row_ptr, int* __restrict__ fill)
{
    int i = blockIdx.x * blockDim.x + threadIdx.x;
    if (i < NN) fill[i] = row_ptr[i];
}

__global__ __launch_bounds__(256) void edge_scatter(
    const int* __restrict__ src, const int* __restrict__ dst,
    const float* __restrict__ ew, const float* __restrict__ dinv,
    int* __restrict__ fill,
    int* __restrict__ src_srt, float* __restrict__ w_srt)
{
    int e = blockIdx.x * blockDim.x + threadIdx.x;
    if (e >= EE) return;
    int s = src[e], t = dst[e];
    float w = -dinv[s] * ew[e] * dinv[t];
    int pos = atomicAdd(&fill[t], 1);
    src_srt[pos] = s;
    w_srt[pos] = w;
}

// ===================== scalar Chebyshev vectors (for H = ones) =====================
__global__ __launch_bounds__(256) void propv_kernel(
    const int* __restrict__ rp, const int* __restrict__ ss, const float* __restrict__ sw,
    const float* __restrict__ tin, const float* __restrict__ tprev, float* __restrict__ tout,
    float alpha, float beta, int ones_in, int ones_prev)
{
    int i = blockIdx.x * blockDim.x + threadIdx.x;
    if (i >= NN) return;
    float acc = 0.f;
    int e0 = rp[i], e1 = rp[i + 1];
    int e = e0;
    for (; e + 4 <= e1; e += 4) {
        float t0 = ones_in ? 1.f : tin[ss[e]];
        float t1v = ones_in ? 1.f : tin[ss[e + 1]];
        float t2v = ones_in ? 1.f : tin[ss[e + 2]];
        float t3v = ones_in ? 1.f : tin[ss[e + 3]];
        acc += sw[e] * t0 + sw[e + 1] * t1v + sw[e + 2] * t2v + sw[e + 3] * t3v;
    }
    for (; e < e1; ++e) {
        float tv = ones_in ? 1.f : tin[ss[e]];
        acc += sw[e] * tv;
    }
    float pv = ones_prev ? 1.f : (tprev ? tprev[i] : 0.f);
    tout[i] = alpha * acc + beta * pv;
}

// colsum of Wh[l, g(0..1), k] -> scol[(l*2+g)*K + k][d]
__global__ __launch_bounds__(128) void colsum_kernel(
    const float* __restrict__ Wh, float* __restrict__ scol)
{
    int b = blockIdx.x;
    int k = b % KK;
    int g = (b / KK) % 2;
    int l = b / (2 * KK);
    int d = threadIdx.x;
    const float* Wp = Wh + ((size_t)((l * 3 + g) * KK + k)) * DD * DD;
    float s = 0.f;
    for (int r = 0; r < DD; ++r) s += Wp[r * DD + d];
    scol[((size_t)((l * 2 + g) * KK + k)) * DD + d] = s;
}

// ===================== weight convert: fp32 -> f16 fragment-major =============
// per 128x128 tile: B-fragment (ko, fc) is contiguous 1KB, lane-ordered:
//   ushort idx = ko*4096 + fc*512 + lane*8 + j   (lane = lk*16 + lr)
//   holds W^T[dout = fc*16+lr][din = ko*32 + lk*8 + j]
// mode 0: src tile = t (Wx); mode 1: src tile = ((t/K)*3+2)*K + t%K (Wh gate 2)
__global__ __launch_bounds__(256) void wconv_frag(
    const float* __restrict__ W, ushort* __restrict__ out, int mode)
{
    int t = blockIdx.x;
    int st = (mode == 0) ? t : ((t / KK) * 3 + 2) * KK + (t % KK);
    const float* Wp = W + (size_t)st * DD * DD;
    ushort* op = out + (size_t)t * DD * DD;
    for (int idx = threadIdx.x; idx < DD * DD; idx += 256) {
        int j  = idx & 7;
        int lr = (idx >> 3) & 15;
        int lk = (idx >> 7) & 3;
        int fc = (idx >> 9) & 7;
        int ko = (idx >> 12) & 3;
        int dout = fc * 16 + lr;
        int din  = ko * 32 + lk * 8 + j;
        op[idx] = f2h(Wp[din * DD + dout]);
    }
}

// ===================== f32 -> f16 bulk convert (row-major) =====================
__global__ __launch_bounds__(256) void f32_to_f16(
    const float* __restrict__ in, ushort* __restrict__ out, int n8)
{
    int i = blockIdx.x * blockDim.x + threadIdx.x;
    if (i >= n8) return;
    float4 a = ((const float4*)in)[i * 2];
    float4 b = ((const float4*)in)[i * 2 + 1];
    f16x8 o;
    o[0] = (_Float16)a.x; o[1] = (_Float16)a.y; o[2] = (_Float16)a.z; o[3] = (_Float16)a.w;
    o[4] = (_Float16)b.x; o[5] = (_Float16)b.y; o[6] = (_Float16)b.z; o[7] = (_Float16)b.w;
    ((f16x8*)out)[i] = o;
}

// ===================== dense (N,D) fp16 propagation (row-major) ===============
// 16 lanes per node (f16x8 = 16B loads, full 256B row per instr); 8-edge unroll;
// nontemporal hints on streaming ss/sw/out so gather targets stay cached.
__global__ __launch_bounds__(256) void prop_mat(
    const int* __restrict__ rp, const int* __restrict__ ss, const float* __restrict__ sw,
    const ushort* __restrict__ x, const ushort* __restrict__ prev,
    ushort* __restrict__ out, float alpha, float beta)
{
    int node = blockIdx.x * 16 + (threadIdx.x >> 4);
    if (node >= NN) return;
    int lane = threadIdx.x & 15;
    int c = lane * 8;
    float acc[8];
#pragma unroll
    for (int j = 0; j < 8; ++j) acc[j] = 0.f;
    int e0 = rp[node], e1 = rp[node + 1];
    int e = e0;
    for (; e + 8 <= e1; e += 8) {
        int s0 = __builtin_nontemporal_load(ss + e);
        int s1 = __builtin_nontemporal_load(ss + e + 1);
        int s2 = __builtin_nontemporal_load(ss + e + 2);
        int s3 = __builtin_nontemporal_load(ss + e + 3);
        int s4 = __builtin_nontemporal_load(ss + e + 4);
        int s5 = __builtin_nontemporal_load(ss + e + 5);
        int s6 = __builtin_nontemporal_load(ss + e + 6);
        int s7 = __builtin_nontemporal_load(ss + e + 7);
        float w0 = __builtin_nontemporal_load(sw + e);
        float w1 = __builtin_nontemporal_load(sw + e + 1);
        float w2 = __builtin_nontemporal_load(sw + e + 2);
        float w3 = __builtin_nontemporal_load(sw + e + 3);
        float w4 = __builtin_nontemporal_load(sw + e + 4);
        float w5 = __builtin_nontemporal_load(sw + e + 5);
        float w6 = __builtin_nontemporal_load(sw + e + 6);
        float w7 = __builtin_nontemporal_load(sw + e + 7);
        f16x8 r0 = *(const f16x8*)(x + (size_t)s0 * DD + c);
        f16x8 r1 = *(const f16x8*)(x + (size_t)s1 * DD + c);
        f16x8 r2 = *(const f16x8*)(x + (size_t)s2 * DD + c);
        f16x8 r3 = *(const f16x8*)(x + (size_t)s3 * DD + c);
        f16x8 r4 = *(const f16x8*)(x + (size_t)s4 * DD + c);
        f16x8 r5 = *(const f16x8*)(x + (size_t)s5 * DD + c);
        f16x8 r6 = *(const f16x8*)(x + (size_t)s6 * DD + c);
        f16x8 r7 = *(const f16x8*)(x + (size_t)s7 * DD + c);
#pragma unroll
        for (int j = 0; j < 8; ++j)
            acc[j] += w0 * (float)r0[j] + w1 * (float)r1[j] + w2 * (float)r2[j] + w3 * (float)r3[j]
                    + w4 * (float)r4[j] + w5 * (float)r5[j] + w6 * (float)r6[j] + w7 * (float)r7[j];
    }
    for (; e + 4 <= e1; e += 4) {
        int s0 = ss[e], s1 = ss[e + 1], s2 = ss[e + 2], s3 = ss[e + 3];
        float w0 = sw[e], w1 = sw[e + 1], w2 = sw[e + 2], w3 = sw[e + 3];
        f16x8 r0 = *(const f16x8*)(x + (size_t)s0 * DD + c);
        f16x8 r1 = *(const f16x8*)(x + (size_t)s1 * DD + c);
        f16x8 r2 = *(const f16x8*)(x + (size_t)s2 * DD + c);
        f16x8 r3 = *(const f16x8*)(x + (size_t)s3 * DD + c);
#pragma unroll
        for (int j = 0; j < 8; ++j)
            acc[j] += w0 * (float)r0[j] + w1 * (float)r1[j] + w2 * (float)r2[j] + w3 * (float)r3[j];
    }
    for (; e < e1; ++e) {
        int s = ss[e];
        float w = sw[e];
        f16x8 r = *(const f16x8*)(x + (size_t)s * DD + c);
#pragma unroll
        for (int j = 0; j < 8; ++j) acc[j] += w * (float)r[j];
    }
    union { f16x8 v; u32x4 u; } o;
    if (beta != 0.f && prev) {
        f16x8 pv = *(const f16x8*)(prev + (size_t)node * DD + c);
#pragma unroll
        for (int j = 0; j < 8; ++j) o.v[j] = (_Float16)(alpha * acc[j] + beta * (float)pv[j]);
    } else {
#pragma unroll
        for (int j = 0; j < 8; ++j) o.v[j] = (_Float16)(alpha * acc[j]);
    }
    __builtin_nontemporal_store(o.u, (u32x4*)(out + (size_t)node * DD + c));
}

// ===================== MFMA gate core: fragment-major W staged in LDS =========
// Stage is a linear 32KB copy; each wave reads its B-fragment as a contiguous
// 1KB ds_read_b128 run (sequential lane*16B -> conflict-free pattern).
template<int NFR>
__device__ __forceinline__ void mm_gate(
    const ushort* __restrict__ const* Ts, const ushort* __restrict__ Wg,
    ushort* Bs, const int* rowg, const bool* ok,
    int tid, int lane, int lk, f32x4 acc[NFR][8])
{
#pragma unroll
    for (int fr = 0; fr < NFR; ++fr)
#pragma unroll
        for (int fc = 0; fc < 8; ++fc) acc[fr][fc] = (f32x4){0.f, 0.f, 0.f, 0.f};
#pragma unroll
    for (int k = 0; k < KK; ++k) {
        const ushort* Bg = Wg + (size_t)k * (DD * DD);
        __syncthreads();
#pragma unroll
        for (int i = 0; i < 8; ++i) {
            int off = i * 4096 + tid * 16;
            uint4 v = *(const uint4*)((const char*)Bg + off);
            *(uint4*)((char*)Bs + off) = v;
        }
        f16x8 a[NFR][4];
#pragma unroll
        for (int fr = 0; fr < NFR; ++fr) {
            const ushort* rp2 = Ts[k] + (size_t)rowg[fr] * DD + lk * 8;
#pragma unroll
            for (int ko = 0; ko < 4; ++ko) {
                if (ok[fr]) a[fr][ko] = *(const f16x8*)(rp2 + ko * 32);
                else a[fr][ko] = (f16x8){0, 0, 0, 0, 0, 0, 0, 0};
            }
        }
        __syncthreads();
#pragma unroll
        for (int ko = 0; ko < 4; ++ko) {
#pragma unroll
            for (int fc = 0; fc < 8; ++fc) {
                f16x8 b = *(const f16x8*)(Bs + ko * 4096 + fc * 512 + lane * 8);
#pragma unroll
                for (int fr = 0; fr < NFR; ++fr)
                    acc[fr][fc] = __builtin_amdgcn_mfma_f32_16x16x32_f16(a[fr][ko], b, acc[fr][fc], 0, 0, 0);
            }
        }
    }
}

__device__ __forceinline__ int xcd_swz(int b, int nwg) {
    int xcd = b & 7, idx = b >> 3;
    int q = nwg >> 3, rr = nwg & 7;
    int start = (xcd < rr) ? xcd * (q + 1) : rr * (q + 1) + (xcd - rr) * q;
    return start + idx;
}

// ===================== fused Wx-matmul + per-gate Z/R/H epilogue ==============
// grid = MMG*3 (parallel gate blocks, XCD co-located). Per-block g selects the
// epilogue: g0 -> Xz = sigmoid(acc + biases + ones-side cheb); g1 -> Xr f16
// likewise; g2 -> Xh = raw acc. No serial gates, no extra staging (vs R6).
__global__ __launch_bounds__(256) void cheb_mm_zr(
    const ushort* __restrict__ T0, const ushort* __restrict__ T1,
    const ushort* __restrict__ T2, const ushort* __restrict__ T3,
    const ushort* __restrict__ T4,
    const ushort* __restrict__ Wt, int gate_stride,
    const float* __restrict__ tvec, const float* __restrict__ scol,
    const float* __restrict__ bx, const float* __restrict__ bh, int l,
    float* __restrict__ Xz, ushort* __restrict__ Xr16, float* __restrict__ Xh)
{
    __shared__ ushort Bs[DD * DD];
    const int lin = xcd_swz(blockIdx.x, gridDim.x);
    const int tile = lin / 3;
    const int g = lin - tile * 3;

    const int tid = threadIdx.x;
    const int lane = tid & 63;
    const int wid = tid >> 6;
    const int lr = lane & 15;
    const int lk = lane >> 4;
    const int r0 = tile * 128;
    const ushort* Ts[5] = {T0, T1, T2, T3, T4};

    int rowg[2] = {r0 + wid * 32 + lr, r0 + wid * 32 + lr + 16};
    bool ok[2] = {rowg[0] < NN, rowg[1] < NN};

    f32x4 acc[2][8];
    mm_gate<2>(Ts, Wt + (size_t)g * gate_stride, Bs, rowg, ok, tid, lane, lk, acc);

    if (g == 2) {
        // raw Ht x-side base
#pragma unroll
        for (int fr = 0; fr < 2; ++fr) {
#pragma unroll
            for (int j = 0; j < 4; ++j) {
                int grow = r0 + wid * 32 + fr * 16 + lk * 4 + j;
                if (grow < NN) {
#pragma unroll
                    for (int fc = 0; fc < 8; ++fc)
                        Xh[(size_t)grow * DD + fc * 16 + lr] = acc[fr][fc][j];
                }
            }
        }
    } else {
        const float* sc = scol + (size_t)((l * 2 + g) * KK) * DD;
        const float* b0 = bx + (size_t)(l * 3 + g) * DD;
        const float* b1 = bh + (size_t)(l * 3 + g) * DD;
#pragma unroll
        for (int fr = 0; fr < 2; ++fr) {
#pragma unroll
            for (int j = 0; j < 4; ++j) {
                int grow = r0 + wid * 32 + fr * 16 + lk * 4 + j;
                if (grow < NN) {
                    float t1 = tvec[grow], t2 = tvec[NN + grow];
                    float t3 = tvec[2 * NN + grow], t4 = tvec[3 * NN + grow];
#pragma unroll
                    for (int fc = 0; fc < 8; ++fc) {
                        int d = fc * 16 + lr;
                        size_t idx = (size_t)grow * DD + d;
                        float hh = sc[d] + t1 * sc[DD + d] + t2 * sc[2 * DD + d]
                                 + t3 * sc[3 * DD + d] + t4 * sc[4 * DD + d];
                        float v = acc[fr][fc][j] + b0[d] + b1[d] + hh;
                        v = 1.f / (1.f + expf(-v));
                        if (g == 0) Xz[idx] = v;
                        else Xr16[idx] = f2h(v);
                    }
                }
            }
        }
    }
}

// ===================== fused Wh-matmul + final GRU gate (64-row tiles) ========
__global__ __launch_bounds__(256) void cheb_mm_final(
    const ushort* __restrict__ T0, const ushort* __restrict__ T1,
    const ushort* __restrict__ T2, const ushort* __restrict__ T3,
    const ushort* __restrict__ T4,
    const ushort* __restrict__ Wt,
    const float* __restrict__ Xh, const float* __restrict__ Xz,
    const float* __restrict__ bx, const float* __restrict__ bh, int l,
    float* __restrict__ out, ushort* __restrict__ h16, int write_f32)
{
    __shared__ ushort Bs[DD * DD];
    const int tile = xcd_swz(blockIdx.x, gridDim.x);
    const int tid = threadIdx.x;
    const int lane = tid & 63;
    const int wid = tid >> 6;
    const int lr = lane & 15;
    const int lk = lane >> 4;
    const int r0 = tile * 64;
    const ushort* Ts[5] = {T0, T1, T2, T3, T4};

    int rowg[1] = {r0 + wid * 16 + lr};
    bool ok[1] = {rowg[0] < NN};

    f32x4 acc[1][8];
    mm_gate<1>(Ts, Wt, Bs, rowg, ok, tid, lane, lk, acc);

    const float* b0 = bx + (size_t)(l * 3 + 2) * DD;
    const float* b1 = bh + (size_t)(l * 3 + 2) * DD;
#pragma unroll
    for (int j = 0; j < 4; ++j) {
        int grow = r0 + wid * 16 + lk * 4 + j;
        if (grow < NN) {
#pragma unroll
            for (int fc = 0; fc < 8; ++fc) {
                int d = fc * 16 + lr;
                size_t idx = (size_t)grow * DD + d;
                float pre = acc[0][fc][j] + Xh[idx] + b0[d] + b1[d];
                float ht = tanhf(pre);
                float z = Xz[idx];
                float hn = z + (1.f - z) * ht;
                float h = hn > 0.f ? hn : 0.f;
                if (write_f32) out[idx] = h;
                else h16[idx] = f2h(h);
            }
        }
    }
}

// ===================== host orchestration =====================

extern "C" void kernel_launch(void* const* d_in, const int* in_sizes, int n_in,
                              void* d_out, int out_size, void* d_ws, size_t ws_size,
                              hipStream_t stream)
{
    const int*   ei  = (const int*)d_in[0];
    const float* ew  = (const float*)d_in[1];
    const float* emb = (const float*)d_in[2];
    const float* Wx  = (const float*)d_in[3];
    const float* bx  = (const float*)d_in[4];
    const float* Wh  = (const float*)d_in[5];
    const float* bh  = (const float*)d_in[6];
    float* out = (float*)d_out;

    const int* src = ei;
    const int* dst = ei + EE;

    char* ws = (char*)d_ws;
    size_t off = 0;
    auto alloc = [&](size_t nbytes) -> char* {
        char* p = ws + off;
        off = (off + nbytes + 255) & ~(size_t)255;
        return p;
    };
    float*  deg     = (float*)alloc((size_t)NN * 4);
    float*  dinv    = (float*)alloc((size_t)NN * 4);
    int*    hist    = (int*)alloc((size_t)(NN + 1) * 4);
    int*    row_ptr = (int*)alloc((size_t)(NN + 1) * 4);
    int*    fill    = (int*)alloc((size_t)(NN + 1) * 4);
    int*    src_srt = (int*)alloc((size_t)EE * 4);
    float*  w_srt   = (float*)alloc((size_t)EE * 4);
    float*  tvec    = (float*)alloc((size_t)4 * NN * 4);
    float*  scol    = (float*)alloc((size_t)LL * 2 * KK * DD * 4);
    float*  Xz      = (float*)alloc((size_t)NN * DD * 4);
    float*  Xh      = (float*)alloc((size_t)NN * DD * 4);
    ushort* Th      = (ushort*)alloc((size_t)4 * NN * DD * 2);   // T1..T4 f16
    ushort* x_f16   = (ushort*)alloc((size_t)NN * DD * 2);
    ushort* Xr_f16  = (ushort*)alloc((size_t)NN * DD * 2);
    ushort* WxT     = (ushort*)alloc((size_t)LL * 3 * KK * DD * DD * 2);
    ushort* WhT2    = (ushort*)alloc((size_t)LL * KK * DD * DD * 2);
    (void)ws_size; (void)in_sizes; (void)n_in; (void)out_size;

    ushort* T1 = Th;
    ushort* T2 = Th + (size_t)NN * DD;
    ushort* T3 = Th + (size_t)2 * NN * DD;
    ushort* T4 = Th + (size_t)3 * NN * DD;

    const int EG = (EE + 255) / 256;
    const int NG = (NN + 255) / 256;
    const int PG = (NN + 15) / 16;
    const int MMG = (NN + 127) / 128;
    const int MMG2 = (NN + 63) / 64;
    const int CVG = (NN * DD / 8 + 255) / 256;
    const int GATE_STRIDE = KK * DD * DD;  // ushorts per gate

    hipMemsetAsync(deg, 0, (size_t)NN * 4, stream);
    hipMemsetAsync(hist, 0, (size_t)(NN + 1) * 4, stream);

    edge_pass1<<<EG, 256, 0, stream>>>(src, dst, ew, deg, hist);
    dinv_kernel<<<NG, 256, 0, stream>>>(deg, dinv);
    scan_kernel<<<1, 1024, 0, stream>>>(hist, row_ptr);
    copy_fill<<<NG, 256, 0, stream>>>(row_ptr, fill);
    edge_scatter<<<EG, 256, 0, stream>>>(src, dst, ew, dinv, fill, src_srt, w_srt);

    // scalar Chebyshev vectors t1..t4 (t0 = ones, implicit)
    float* t1 = tvec;
    float* t2 = tvec + NN;
    float* t3 = tvec + 2 * NN;
    float* t4 = tvec + 3 * NN;
    propv_kernel<<<NG, 256, 0, stream>>>(row_ptr, src_srt, w_srt, nullptr, nullptr, t1, 1.f,  0.f, 1, 0);
    propv_kernel<<<NG, 256, 0, stream>>>(row_ptr, src_srt, w_srt, t1, nullptr,      t2, 2.f, -1.f, 0, 1);
    propv_kernel<<<NG, 256, 0, stream>>>(row_ptr, src_srt, w_srt, t2, t1,           t3, 2.f, -1.f, 0, 0);
    propv_kernel<<<NG, 256, 0, stream>>>(row_ptr, src_srt, w_srt, t3, t2,           t4, 2.f, -1.f, 0, 0);

    colsum_kernel<<<LL * 2 * KK, 128, 0, stream>>>(Wh, scol);

    // weights -> f16 fragment-major (staged linearly to LDS by mm kernels)
    wconv_frag<<<LL * 3 * KK, 256, 0, stream>>>(Wx, WxT, 0);
    wconv_frag<<<LL * KK, 256, 0, stream>>>(Wh, WhT2, 1);

    // emb -> f16 (row-major)
    f32_to_f16<<<CVG, 256, 0, stream>>>(emb, x_f16, NN * DD / 8);

    for (int l = 0; l < LL; ++l) {
        // Chebyshev basis of x (f16 storage, fp32 accumulate)
        prop_mat<<<PG, 256, 0, stream>>>(row_ptr, src_srt, w_srt, x_f16, nullptr, T1, 1.f,  0.f);
        prop_mat<<<PG, 256, 0, stream>>>(row_ptr, src_srt, w_srt, T1,    x_f16,   T2, 2.f, -1.f);
        prop_mat<<<PG, 256, 0, stream>>>(row_ptr, src_srt, w_srt, T2,    T1,      T3, 2.f, -1.f);
        prop_mat<<<PG, 256, 0, stream>>>(row_ptr, src_srt, w_srt, T3,    T2,      T4, 2.f, -1.f);

        // fused: Xg matmuls + per-gate Z/R/H epilogues (parallel gate blocks)
        cheb_mm_zr<<<MMG * 3, 256, 0, stream>>>(x_f16, T1, T2, T3, T4,
                                             WxT + (size_t)l * 3 * GATE_STRIDE, GATE_STRIDE,
                                             tvec, scol, bx, bh, l,
                                             Xz, Xr_f16, Xh);

        // Chebyshev basis of R (H*R == R since H == ones)
        prop_mat<<<PG, 256, 0, stream>>>(row_ptr, src_srt, w_srt, Xr_f16, nullptr, T1, 1.f,  0.f);
        prop_mat<<<PG, 256, 0, stream>>>(row_ptr, src_srt, w_srt, T1,     Xr_f16,  T2, 2.f, -1.f);
        prop_mat<<<PG, 256, 0, stream>>>(row_ptr, src_srt, w_srt, T2,     T1,      T3, 2.f, -1.f);
        prop_mat<<<PG, 256, 0, stream>>>(row_ptr, src_srt, w_srt, T3,     T2,      T4, 2.f, -1.f);

        // fused: Xh + sum_k TR_k @ Wh[l,2,k] + final GRU gate (64-row tiles)
        cheb_mm_final<<<MMG2, 256, 0, stream>>>(Xr_f16, T1, T2, T3, T4,
                                               WhT2 + (size_t)l * GATE_STRIDE,
                                               Xh, Xz, bx, bh, l,
                                               out, x_f16, (l == LL - 1) ? 1 : 0);
    }
}

// Round 13
// 884.211 us; speedup vs baseline: 1.2259x; 1.0164x over previous
//
#include <hip/hip_runtime.h>
#include <math.h>

#define NN 50000
#define EE 500000
#define DD 128
#define KK 5
#define LL 2

// 4-panel layout for f16 N x D state: [4 panels][NN][32] (panel p = cols 32p..32p+31)
#define PSZ32 ((size_t)NN * 32)

typedef _Float16 f16x8 __attribute__((ext_vector_type(8)));
typedef float f32x4 __attribute__((ext_vector_type(4)));
typedef unsigned int u32x4 __attribute__((ext_vector_type(4)));

__device__ __forceinline__ ushort f2h(float x) {
    union { _Float16 h; ushort u; } v; v.h = (_Float16)x; return v.u;
}

// ===================== graph preprocessing =====================

__global__ __launch_bounds__(256) void edge_pass1(
    const int* __restrict__ src, const int* __restrict__ dst,
    const float* __restrict__ ew,
    float* __restrict__ deg, int* __restrict__ hist)
{
    int e = blockIdx.x * blockDim.x + threadIdx.x;
    if (e >= EE) return;
    atomicAdd(&deg[src[e]], ew[e]);
    atomicAdd(&hist[dst[e]], 1);
}

__global__ __launch_bounds__(256) void dinv_kernel(
    const float* __restrict__ deg, float* __restrict__ dinv)
{
    int i = blockIdx.x * blockDim.x + threadIdx.x;
    if (i >= NN) return;
    float d = deg[i];
    dinv[i] = (d > 0.f) ? (1.f / sqrtf(d)) : 0.f;
}

// register-chunked single-block scan; also emits fill[] (= row start) directly
#define SCAN_C ((NN + 1023) / 1024)
__global__ __launch_bounds__(1024) void scan_kernel(
    const int* __restrict__ hist, int* __restrict__ row_ptr, int* __restrict__ fill)
{
    __shared__ int sums[1024];
    const int t = threadIdx.x;
    const int base = t * SCAN_C;
    int local[SCAN_C];
    int s = 0;
#pragma unroll
    for (int j = 0; j < SCAN_C; ++j) {
        int i = base + j;
        int v = (i < NN) ? hist[i] : 0;
        s += v;
        local[j] = s;
    }
    sums[t] = s;
    __syncthreads();
    for (int off = 1; off < 1024; off <<= 1) {
        int v = (t >= off) ? sums[t - off] : 0;
        __syncthreads();
        sums[t] += v;
        __syncthreads();
    }
    int excl = sums[t] - s;
    if (t == 0) row_ptr[0] = 0;
#pragma unroll
    for (int j = 0; j < SCAN_C; ++j) {
        int i = base + j;
        if (i < NN) {
            row_ptr[i + 1] = excl + local[j];
            fill[i] = excl + (j ? local[j - 1] : 0);
        }
    }
}

__global__ __launch_bounds__(256) void edge_scatter(
    const int* __restrict__ src, const int* __restrict__ dst,
    const float* __restrict__ ew, const float* __restrict__ dinv,
    int* __restrict__ fill,
    int* __restrict__ src_srt, float* __restrict__ w_srt)
{
    int e = blockIdx.x * blockDim.x + threadIdx.x;
    if (e >= EE) return;
    int s = src[e], t = dst[e];
    float w = -dinv[s] * ew[e] * dinv[t];
    int pos = atomicAdd(&fill[t], 1);
    src_srt[pos] = s;
    w_srt[pos] = w;
}

// ===================== scalar Chebyshev vectors (for H = ones) =====================
__global__ __launch_bounds__(256) void propv_kernel(
    const int* __restrict__ rp, const int* __restrict__ ss, const float* __restrict__ sw,
    const float* __restrict__ tin, const float* __restrict__ tprev, float* __restrict__ tout,
    float alpha, float beta, int ones_in, int ones_prev)
{
    int i = blockIdx.x * blockDim.x + threadIdx.x;
    if (i >= NN) return;
    float acc = 0.f;
    int e0 = rp[i], e1 = rp[i + 1];
    int e = e0;
    for (; e + 4 <= e1; e += 4) {
        float t0 = ones_in ? 1.f : tin[ss[e]];
        float t1v = ones_in ? 1.f : tin[ss[e + 1]];
        float t2v = ones_in ? 1.f : tin[ss[e + 2]];
        float t3v = ones_in ? 1.f : tin[ss[e + 3]];
        acc += sw[e] * t0 + sw[e + 1] * t1v + sw[e + 2] * t2v + sw[e + 3] * t3v;
    }
    for (; e < e1; ++e) {
        float tv = ones_in ? 1.f : tin[ss[e]];
        acc += sw[e] * tv;
    }
    float pv = ones_prev ? 1.f : (tprev ? tprev[i] : 0.f);
    tout[i] = alpha * acc + beta * pv;
}

// colsum of Wh[l, g(0..1), k] -> scol[(l*2+g)*K + k][d]
__global__ __launch_bounds__(128) void colsum_kernel(
    const float* __restrict__ Wh, float* __restrict__ scol)
{
    int b = blockIdx.x;
    int k = b % KK;
    int g = (b / KK) % 2;
    int l = b / (2 * KK);
    int d = threadIdx.x;
    const float* Wp = Wh + ((size_t)((l * 3 + g) * KK + k)) * DD * DD;
    float s = 0.f;
    for (int r = 0; r < DD; ++r) s += Wp[r * DD + d];
    scol[((size_t)((l * 2 + g) * KK + k)) * DD + d] = s;
}

// ===================== weight convert: fp32 -> fp16, transposed + pre-swizzled ==
__global__ __launch_bounds__(256) void wconv_f16(
    const float* __restrict__ W, ushort* __restrict__ out, int mode)
{
    int t = blockIdx.x;
    int st = (mode == 0) ? t : ((t / KK) * 3 + 2) * KK + (t % KK);
    const float* Wp = W + (size_t)st * DD * DD;
    ushort* op = out + (size_t)t * DD * DD;
    for (int idx = threadIdx.x; idx < DD * DD; idx += 256) {
        int rb = idx >> 7, c = idx & 127;
        float w = Wp[c * DD + rb];          // transpose: [dout][din] from [din][dout]
        int byte = rb * 256 + (((c * 2) ^ ((rb & 7) << 4)));
        *(ushort*)((char*)op + byte) = f2h(w);
    }
}

// ===================== f32 (row-major) -> f16 4-panels =====================
__global__ __launch_bounds__(256) void f32_to_f16_panel(
    const float* __restrict__ in, ushort* __restrict__ out, int n8)
{
    int j = blockIdx.x * blockDim.x + threadIdx.x;
    if (j >= n8) return;
    int flat = j * 8;
    int i = flat >> 7;        // node
    int d0 = flat & 127;      // 0,8,...,120
    float4 a = *(const float4*)(in + (size_t)i * DD + d0);
    float4 b = *(const float4*)(in + (size_t)i * DD + d0 + 4);
    f16x8 o;
    o[0] = (_Float16)a.x; o[1] = (_Float16)a.y; o[2] = (_Float16)a.z; o[3] = (_Float16)a.w;
    o[4] = (_Float16)b.x; o[5] = (_Float16)b.y; o[6] = (_Float16)b.z; o[7] = (_Float16)b.w;
    *(f16x8*)(out + (size_t)(d0 >> 5) * PSZ32 + (size_t)i * 32 + (d0 & 31)) = o;
}

// ===================== dense fp16 propagation, 4x32-col panel layout ==========
__global__ __launch_bounds__(256) void prop_mat(
    const int* __restrict__ rp, const int* __restrict__ ss, const float* __restrict__ sw,
    const ushort* __restrict__ x, const ushort* __restrict__ prev,
    ushort* __restrict__ out, float alpha, float beta)
{
    const int p = blockIdx.x & 3;
    const int node = (blockIdx.x >> 2) * 64 + (threadIdx.x >> 2);
    if (node >= NN) return;
    const int lane8 = (threadIdx.x & 3) * 8;
    const ushort* xp = x + (size_t)p * PSZ32 + lane8;
    float acc[8];
#pragma unroll
    for (int j = 0; j < 8; ++j) acc[j] = 0.f;
    int e0 = rp[node], e1 = rp[node + 1];
    int e = e0;
    for (; e + 8 <= e1; e += 8) {
        int s0 = ss[e], s1 = ss[e + 1], s2 = ss[e + 2], s3 = ss[e + 3];
        int s4 = ss[e + 4], s5 = ss[e + 5], s6 = ss[e + 6], s7 = ss[e + 7];
        float w0 = sw[e], w1 = sw[e + 1], w2 = sw[e + 2], w3 = sw[e + 3];
        float w4 = sw[e + 4], w5 = sw[e + 5], w6 = sw[e + 6], w7 = sw[e + 7];
        f16x8 r0 = *(const f16x8*)(xp + (size_t)s0 * 32);
        f16x8 r1 = *(const f16x8*)(xp + (size_t)s1 * 32);
        f16x8 r2 = *(const f16x8*)(xp + (size_t)s2 * 32);
        f16x8 r3 = *(const f16x8*)(xp + (size_t)s3 * 32);
        f16x8 r4 = *(const f16x8*)(xp + (size_t)s4 * 32);
        f16x8 r5 = *(const f16x8*)(xp + (size_t)s5 * 32);
        f16x8 r6 = *(const f16x8*)(xp + (size_t)s6 * 32);
        f16x8 r7 = *(const f16x8*)(xp + (size_t)s7 * 32);
#pragma unroll
        for (int j = 0; j < 8; ++j)
            acc[j] += w0 * (float)r0[j] + w1 * (float)r1[j] + w2 * (float)r2[j] + w3 * (float)r3[j]
                    + w4 * (float)r4[j] + w5 * (float)r5[j] + w6 * (float)r6[j] + w7 * (float)r7[j];
    }
    for (; e + 4 <= e1; e += 4) {
        int s0 = ss[e], s1 = ss[e + 1], s2 = ss[e + 2], s3 = ss[e + 3];
        float w0 = sw[e], w1 = sw[e + 1], w2 = sw[e + 2], w3 = sw[e + 3];
        f16x8 r0 = *(const f16x8*)(xp + (size_t)s0 * 32);
        f16x8 r1 = *(const f16x8*)(xp + (size_t)s1 * 32);
        f16x8 r2 = *(const f16x8*)(xp + (size_t)s2 * 32);
        f16x8 r3 = *(const f16x8*)(xp + (size_t)s3 * 32);
#pragma unroll
        for (int j = 0; j < 8; ++j)
            acc[j] += w0 * (float)r0[j] + w1 * (float)r1[j] + w2 * (float)r2[j] + w3 * (float)r3[j];
    }
    for (; e < e1; ++e) {
        int s = ss[e];
        float w = sw[e];
        f16x8 r = *(const f16x8*)(xp + (size_t)s * 32);
#pragma unroll
        for (int j = 0; j < 8; ++j) acc[j] += w * (float)r[j];
    }
    f16x8 o;
    if (beta != 0.f && prev) {
        f16x8 pv = *(const f16x8*)(prev + (size_t)p * PSZ32 + (size_t)node * 32 + lane8);
#pragma unroll
        for (int j = 0; j < 8; ++j) o[j] = (_Float16)(alpha * acc[j] + beta * (float)pv[j]);
    } else {
#pragma unroll
        for (int j = 0; j < 8; ++j) o[j] = (_Float16)(alpha * acc[j]);
    }
    *(f16x8*)(out + (size_t)p * PSZ32 + (size_t)node * 32 + lane8) = o;
}

// ===================== shared MFMA gate core: 2-k-tile LDS staging ============
// 64KB LDS, 3 barrier-rounds for 5 k-tiles (128 MFMAs per barrier-pair).
// Swizzled W layout identical to R10; reads offset by tile slot t*32768.
template<int NFR>
__device__ __forceinline__ void mm_gate(
    const ushort* __restrict__ const* Ts, const ushort* __restrict__ Wg,
    ushort* Bs, const int* rowg, const bool* ok,
    int tid, int lk, int lr, f32x4 acc[NFR][8])
{
#pragma unroll
    for (int fr = 0; fr < NFR; ++fr)
#pragma unroll
        for (int fc = 0; fc < 8; ++fc) acc[fr][fc] = (f32x4){0.f, 0.f, 0.f, 0.f};
#pragma unroll
    for (int rnd = 0; rnd < 3; ++rnd) {
        const int kb = rnd * 2;
        const int ntile = (rnd == 2) ? 1 : 2;
        __syncthreads();
#pragma unroll
        for (int t = 0; t < 2; ++t) {
            if (t < ntile) {
                const ushort* Bg = Wg + (size_t)(kb + t) * (DD * DD);
#pragma unroll
                for (int i = 0; i < 8; ++i) {
                    int off = i * 4096 + tid * 16;
                    uint4 v = *(const uint4*)((const char*)Bg + off);
                    *(uint4*)((char*)Bs + t * 32768 + off) = v;
                }
            }
        }
        __syncthreads();
#pragma unroll
        for (int t = 0; t < 2; ++t) {
            if (t < ntile) {
                const int k = kb + t;
                f16x8 a[NFR][4];
#pragma unroll
                for (int fr = 0; fr < NFR; ++fr) {
#pragma unroll
                    for (int ko = 0; ko < 4; ++ko) {
                        const ushort* ap = Ts[k] + (size_t)ko * PSZ32
                                         + (size_t)rowg[fr] * 32 + lk * 8;
                        if (ok[fr]) a[fr][ko] = *(const f16x8*)ap;
                        else a[fr][ko] = (f16x8){0, 0, 0, 0, 0, 0, 0, 0};
                    }
                }
                const char* base = (const char*)Bs + t * 32768;
#pragma unroll
                for (int ko = 0; ko < 4; ++ko) {
                    const int cb = ko * 64 + lk * 16;
#pragma unroll
                    for (int fc = 0; fc < 8; ++fc) {
                        int rb = fc * 16 + lr;
                        int byte = (rb * 256 + cb) ^ ((rb & 7) << 4);
                        f16x8 bfrag = *(const f16x8*)(base + byte);
#pragma unroll
                        for (int fr = 0; fr < NFR; ++fr)
                            acc[fr][fc] = __builtin_amdgcn_mfma_f32_16x16x32_f16(a[fr][ko], bfrag, acc[fr][fc], 0, 0, 0);
                    }
                }
            }
        }
    }
}

__device__ __forceinline__ int xcd_swz(int b, int nwg) {
    int xcd = b & 7, idx = b >> 3;
    int q = nwg >> 3, rr = nwg & 7;
    int start = (xcd < rr) ? xcd * (q + 1) : rr * (q + 1) + (xcd - rr) * q;
    return start + idx;
}

// ===================== fp16 MFMA Chebyshev matmul (parallel gates, 128-row) ===
__global__ __launch_bounds__(256) void cheb_mm_mfma(
    const ushort* __restrict__ T0, const ushort* __restrict__ T1,
    const ushort* __restrict__ T2, const ushort* __restrict__ T3,
    const ushort* __restrict__ T4,
    const ushort* __restrict__ Wt, int gate_stride,
    float* __restrict__ outbase, size_t out_stride, int ngates)
{
    __shared__ ushort Bs[DD * DD * 2];   // 64KB, 2 k-tile slots
    const int lin = xcd_swz(blockIdx.x, gridDim.x);
    const int tile = lin / ngates;
    const int g = lin - tile * ngates;

    const int tid = threadIdx.x;
    const int lane = tid & 63;
    const int wid = tid >> 6;
    const int lr = lane & 15;
    const int lk = lane >> 4;
    const int r0 = tile * 128;
    const ushort* Ts[5] = {T0, T1, T2, T3, T4};

    int rowg[2] = {r0 + wid * 32 + lr, r0 + wid * 32 + lr + 16};
    bool ok[2] = {rowg[0] < NN, rowg[1] < NN};

    f32x4 acc[2][8];
    mm_gate<2>(Ts, Wt + (size_t)g * gate_stride, Bs, rowg, ok, tid, lk, lr, acc);

    float* outp = outbase + (size_t)g * out_stride;
#pragma unroll
    for (int fr = 0; fr < 2; ++fr) {
#pragma unroll
        for (int j = 0; j < 4; ++j) {
            int grow = r0 + wid * 32 + fr * 16 + lk * 4 + j;
            if (grow < NN) {
#pragma unroll
                for (int fc = 0; fc < 8; ++fc) {
                    int col = fc * 16 + lr;
                    outp[(size_t)grow * DD + col] = acc[fr][fc][j];
                }
            }
        }
    }
}

// ===================== fused Wh-matmul + final GRU gate (64-row tiles) ========
__global__ __launch_bounds__(256) void cheb_mm_final(
    const ushort* __restrict__ T0, const ushort* __restrict__ T1,
    const ushort* __restrict__ T2, const ushort* __restrict__ T3,
    const ushort* __restrict__ T4,
    const ushort* __restrict__ Wt,
    const float* __restrict__ Xh, const float* __restrict__ Xz,
    const float* __restrict__ bx, const float* __restrict__ bh, int l,
    float* __restrict__ out, ushort* __restrict__ h16, int write_f32)
{
    __shared__ ushort Bs[DD * DD * 2];   // 64KB, 2 k-tile slots
    const int tile = xcd_swz(blockIdx.x, gridDim.x);
    const int tid = threadIdx.x;
    const int lane = tid & 63;
    const int wid = tid >> 6;
    const int lr = lane & 15;
    const int lk = lane >> 4;
    const int r0 = tile * 64;
    const ushort* Ts[5] = {T0, T1, T2, T3, T4};

    int rowg[1] = {r0 + wid * 16 + lr};
    bool ok[1] = {rowg[0] < NN};

    f32x4 acc[1][8];
    mm_gate<1>(Ts, Wt, Bs, rowg, ok, tid, lk, lr, acc);

    const float* b0 = bx + (size_t)(l * 3 + 2) * DD;
    const float* b1 = bh + (size_t)(l * 3 + 2) * DD;
#pragma unroll
    for (int j = 0; j < 4; ++j) {
        int grow = r0 + wid * 16 + lk * 4 + j;
        if (grow < NN) {
#pragma unroll
            for (int fc = 0; fc < 8; ++fc) {
                int d = fc * 16 + lr;
                size_t idx = (size_t)grow * DD + d;
                float pre = acc[0][fc][j] + Xh[idx] + b0[d] + b1[d];
                float ht = tanhf(pre);
                float z = Xz[idx];
                float hn = z + (1.f - z) * ht;
                float h = hn > 0.f ? hn : 0.f;
                if (write_f32) out[idx] = h;
                else h16[(size_t)(d >> 5) * PSZ32 + (size_t)grow * 32 + (d & 31)] = f2h(h);
            }
        }
    }
}

// ===================== gate kernel: Z,R from raw matmul results ===============
__global__ __launch_bounds__(256) void gate_zr_kernel(
    float* __restrict__ Xz, const float* __restrict__ Xr, ushort* __restrict__ Xr_f16,
    const float* __restrict__ tvec, const float* __restrict__ scol,
    const float* __restrict__ bx, const float* __restrict__ bh, int l)
{
    int idx = blockIdx.x * blockDim.x + threadIdx.x;
    if (idx >= NN * DD) return;
    int i = idx >> 7;
    int d = idx & 127;
    float t1 = tvec[i], t2 = tvec[NN + i], t3 = tvec[2 * NN + i], t4 = tvec[3 * NN + i];

    const float* s0 = scol + (size_t)((l * 2 + 0) * KK) * DD;
    float hz = s0[d] + t1 * s0[DD + d] + t2 * s0[2 * DD + d] + t3 * s0[3 * DD + d] + t4 * s0[4 * DD + d];
    float z = Xz[idx] + bx[(l * 3 + 0) * DD + d] + bh[(l * 3 + 0) * DD + d] + hz;
    Xz[idx] = 1.f / (1.f + expf(-z));

    const float* s1 = scol + (size_t)((l * 2 + 1) * KK) * DD;
    float hr = s1[d] + t1 * s1[DD + d] + t2 * s1[2 * DD + d] + t3 * s1[3 * DD + d] + t4 * s1[4 * DD + d];
    float r = Xr[idx] + bx[(l * 3 + 1) * DD + d] + bh[(l * 3 + 1) * DD + d] + hr;
    Xr_f16[(size_t)(d >> 5) * PSZ32 + (size_t)i * 32 + (d & 31)] = f2h(1.f / (1.f + expf(-r)));
}

// ===================== host orchestration =====================

extern "C" void kernel_launch(void* const* d_in, const int* in_sizes, int n_in,
                              void* d_out, int out_size, void* d_ws, size_t ws_size,
                              hipStream_t stream)
{
    const int*   ei  = (const int*)d_in[0];
    const float* ew  = (const float*)d_in[1];
    const float* emb = (const float*)d_in[2];
    const float* Wx  = (const float*)d_in[3];
    const float* bx  = (const float*)d_in[4];
    const float* Wh  = (const float*)d_in[5];
    const float* bh  = (const float*)d_in[6];
    float* out = (float*)d_out;

    const int* src = ei;
    const int* dst = ei + EE;

    char* ws = (char*)d_ws;
    size_t off = 0;
    auto alloc = [&](size_t nbytes) -> char* {
        char* p = ws + off;
        off = (off + nbytes + 255) & ~(size_t)255;
        return p;
    };
    float*  deg     = (float*)alloc((size_t)NN * 4);
    float*  dinv    = (float*)alloc((size_t)NN * 4);
    int*    hist    = (int*)alloc((size_t)(NN + 1) * 4);
    int*    row_ptr = (int*)alloc((size_t)(NN + 1) * 4);
    int*    fill    = (int*)alloc((size_t)(NN + 1) * 4);
    int*    src_srt = (int*)alloc((size_t)EE * 4);
    float*  w_srt   = (float*)alloc((size_t)EE * 4);
    float*  tvec    = (float*)alloc((size_t)4 * NN * 4);
    float*  scol    = (float*)alloc((size_t)LL * 2 * KK * DD * 4);
    float*  X       = (float*)alloc((size_t)3 * NN * DD * 4);    // Xz,Xr,Xh fp32
    ushort* Th      = (ushort*)alloc((size_t)4 * NN * DD * 2);   // T1..T4 f16 panels
    ushort* x_f16   = (ushort*)alloc((size_t)NN * DD * 2);       // panels
    ushort* Xr_f16  = (ushort*)alloc((size_t)NN * DD * 2);       // panels
    ushort* WxT     = (ushort*)alloc((size_t)LL * 3 * KK * DD * DD * 2);
    ushort* WhT2    = (ushort*)alloc((size_t)LL * KK * DD * DD * 2);
    (void)ws_size; (void)in_sizes; (void)n_in; (void)out_size;

    float* Xz = X;
    float* Xr = X + (size_t)NN * DD;
    float* Xh = X + (size_t)2 * NN * DD;
    ushort* T1 = Th;
    ushort* T2 = Th + (size_t)NN * DD;
    ushort* T3 = Th + (size_t)2 * NN * DD;
    ushort* T4 = Th + (size_t)3 * NN * DD;

    const int EG = (EE + 255) / 256;
    const int NG = (NN + 255) / 256;
    const int PG = ((NN + 63) / 64) * 4;       // 4-panel prop grid
    const int ELG = (NN * DD + 255) / 256;
    const int MMG = (NN + 127) / 128;
    const int MMG2 = (NN + 63) / 64;
    const int CVG = (NN * DD / 8 + 255) / 256;
    const int GATE_STRIDE = KK * DD * DD;  // ushorts per gate

    hipMemsetAsync(deg, 0, (size_t)NN * 4, stream);
    hipMemsetAsync(hist, 0, (size_t)(NN + 1) * 4, stream);

    edge_pass1<<<EG, 256, 0, stream>>>(src, dst, ew, deg, hist);
    dinv_kernel<<<NG, 256, 0, stream>>>(deg, dinv);
    scan_kernel<<<1, 1024, 0, stream>>>(hist, row_ptr, fill);
    edge_scatter<<<EG, 256, 0, stream>>>(src, dst, ew, dinv, fill, src_srt, w_srt);

    // scalar Chebyshev vectors t1..t4 (t0 = ones, implicit)
    float* t1 = tvec;
    float* t2 = tvec + NN;
    float* t3 = tvec + 2 * NN;
    float* t4 = tvec + 3 * NN;
    propv_kernel<<<NG, 256, 0, stream>>>(row_ptr, src_srt, w_srt, nullptr, nullptr, t1, 1.f,  0.f, 1, 0);
    propv_kernel<<<NG, 256, 0, stream>>>(row_ptr, src_srt, w_srt, t1, nullptr,      t2, 2.f, -1.f, 0, 1);
    propv_kernel<<<NG, 256, 0, stream>>>(row_ptr, src_srt, w_srt, t2, t1,           t3, 2.f, -1.f, 0, 0);
    propv_kernel<<<NG, 256, 0, stream>>>(row_ptr, src_srt, w_srt, t3, t2,           t4, 2.f, -1.f, 0, 0);

    colsum_kernel<<<LL * 2 * KK, 128, 0, stream>>>(Wh, scol);

    // weights -> f16, transposed + pre-swizzled (LDS staging layout)
    wconv_f16<<<LL * 3 * KK, 256, 0, stream>>>(Wx, WxT, 0);
    wconv_f16<<<LL * KK, 256, 0, stream>>>(Wh, WhT2, 1);

    // emb -> f16 panels
    f32_to_f16_panel<<<CVG, 256, 0, stream>>>(emb, x_f16, NN * DD / 8);

    for (int l = 0; l < LL; ++l) {
        // Chebyshev basis of x (f16 panels, fp32 accumulate)
        prop_mat<<<PG, 256, 0, stream>>>(row_ptr, src_srt, w_srt, x_f16, nullptr, T1, 1.f,  0.f);
        prop_mat<<<PG, 256, 0, stream>>>(row_ptr, src_srt, w_srt, T1,    x_f16,   T2, 2.f, -1.f);
        prop_mat<<<PG, 256, 0, stream>>>(row_ptr, src_srt, w_srt, T2,    T1,      T3, 2.f, -1.f);
        prop_mat<<<PG, 256, 0, stream>>>(row_ptr, src_srt, w_srt, T3,    T2,      T4, 2.f, -1.f);

        // Xg = sum_k T_k @ Wx[l,g,k], g=0..2 (parallel gate blocks, XCD co-located)
        cheb_mm_mfma<<<MMG * 3, 256, 0, stream>>>(x_f16, T1, T2, T3, T4,
                                             WxT + (size_t)l * 3 * GATE_STRIDE, GATE_STRIDE,
                                             Xz, (size_t)NN * DD, 3);

        // Z, R (rank-K ones-side cheb + biases); Xz sigmoid in-place + Xr f16 panels
        gate_zr_kernel<<<ELG, 256, 0, stream>>>(Xz, Xr, Xr_f16, tvec, scol, bx, bh, l);

        // Chebyshev basis of R (H*R == R since H == ones)
        prop_mat<<<PG, 256, 0, stream>>>(row_ptr, src_srt, w_srt, Xr_f16, nullptr, T1, 1.f,  0.f);
        prop_mat<<<PG, 256, 0, stream>>>(row_ptr, src_srt, w_srt, T1,     Xr_f16,  T2, 2.f, -1.f);
        prop_mat<<<PG, 256, 0, stream>>>(row_ptr, src_srt, w_srt, T2,     T1,      T3, 2.f, -1.f);
        prop_mat<<<PG, 256, 0, stream>>>(row_ptr, src_srt, w_srt, T3,     T2,      T4, 2.f, -1.f);

        // fused: Xh + sum_k TR_k @ Wh[l,2,k] + final GRU gate (64-row tiles)
        cheb_mm_final<<<MMG2, 256, 0, stream>>>(Xr_f16, T1, T2, T3, T4,
                                               WhT2 + (size_t)l * GATE_STRIDE,
                                               Xh, Xz, bx, bh, l,
                                               out, x_f16, (l == LL - 1) ? 1 : 0);
    }
}

// Round 14
// 809.175 us; speedup vs baseline: 1.3396x; 1.0927x over previous
//
#include <hip/hip_runtime.h>
#include <math.h>

#define NN 50000
#define EE 500000
#define DD 128
#define KK 5
#define LL 2

// 4-panel layout for f16 N x D state: [4 panels][NN][32] (panel p = cols 32p..32p+31)
#define PSZ32 ((size_t)NN * 32)

// multi-block scan geometry
#define SCB 256
#define SNB ((NN + SCB - 1) / SCB)

typedef _Float16 f16x8 __attribute__((ext_vector_type(8)));
typedef float f32x4 __attribute__((ext_vector_type(4)));
typedef unsigned int u32x4 __attribute__((ext_vector_type(4)));

__device__ __forceinline__ ushort f2h(float x) {
    union { _Float16 h; ushort u; } v; v.h = (_Float16)x; return v.u;
}

// ===================== graph preprocessing =====================

__global__ __launch_bounds__(256) void edge_pass1(
    const int* __restrict__ src, const int* __restrict__ dst,
    const float* __restrict__ ew,
    float* __restrict__ deg, int* __restrict__ hist)
{
    int e = blockIdx.x * blockDim.x + threadIdx.x;
    if (e >= EE) return;
    atomicAdd(&deg[src[e]], ew[e]);
    atomicAdd(&hist[dst[e]], 1);
}

__global__ __launch_bounds__(256) void dinv_kernel(
    const float* __restrict__ deg, float* __restrict__ dinv)
{
    int i = blockIdx.x * blockDim.x + threadIdx.x;
    if (i >= NN) return;
    float d = deg[i];
    dinv[i] = (d > 0.f) ? (1.f / sqrtf(d)) : 0.f;
}

// ---- 3-pass coalesced multi-block scan ----
__global__ __launch_bounds__(SCB) void scan_p1(
    const int* __restrict__ hist, int* __restrict__ bsum)
{
    __shared__ int buf[SCB];
    int i = blockIdx.x * SCB + threadIdx.x;
    int v = (i < NN) ? hist[i] : 0;
    buf[threadIdx.x] = v;
    __syncthreads();
    for (int off = SCB / 2; off > 0; off >>= 1) {
        if (threadIdx.x < off) buf[threadIdx.x] += buf[threadIdx.x + off];
        __syncthreads();
    }
    if (threadIdx.x == 0) bsum[blockIdx.x] = buf[0];
}

__global__ __launch_bounds__(256) void scan_p2(
    int* __restrict__ bsum)   // in-place -> exclusive prefix
{
    __shared__ int buf[256];
    int t = threadIdx.x;
    int v = (t < SNB) ? bsum[t] : 0;
    buf[t] = v;
    __syncthreads();
    for (int off = 1; off < 256; off <<= 1) {
        int u = (t >= off) ? buf[t - off] : 0;
        __syncthreads();
        buf[t] += u;
        __syncthreads();
    }
    if (t < SNB) bsum[t] = buf[t] - v;   // exclusive
}

__global__ __launch_bounds__(SCB) void scan_p3(
    const int* __restrict__ hist, const int* __restrict__ bsum,
    int* __restrict__ row_ptr, int* __restrict__ fill)
{
    __shared__ int buf[SCB];
    int t = threadIdx.x;
    int i = blockIdx.x * SCB + t;
    int v = (i < NN) ? hist[i] : 0;
    buf[t] = v;
    __syncthreads();
    for (int off = 1; off < SCB; off <<= 1) {
        int u = (t >= off) ? buf[t - off] : 0;
        __syncthreads();
        buf[t] += u;
        __syncthreads();
    }
    int incl = buf[t] + bsum[blockIdx.x];
    if (i < NN) {
        row_ptr[i + 1] = incl;
        fill[i] = incl - v;
    }
    if (i == 0) row_ptr[0] = 0;
}

__global__ __launch_bounds__(256) void edge_scatter(
    const int* __restrict__ src, const int* __restrict__ dst,
    const float* __restrict__ ew, const float* __restrict__ dinv,
    int* __restrict__ fill,
    int* __restrict__ src_srt, float* __restrict__ w_srt)
{
    int e = blockIdx.x * blockDim.x + threadIdx.x;
    if (e >= EE) return;
    int s = src[e], t = dst[e];
    float w = -dinv[s] * ew[e] * dinv[t];
    int pos = atomicAdd(&fill[t], 1);
    src_srt[pos] = s;
    w_srt[pos] = w;
}

// ===================== scalar Chebyshev vectors (for H = ones) =====================
__global__ __launch_bounds__(256) void propv_kernel(
    const int* __restrict__ rp, const int* __restrict__ ss, const float* __restrict__ sw,
    const float* __restrict__ tin, const float* __restrict__ tprev, float* __restrict__ tout,
    float alpha, float beta, int ones_in, int ones_prev)
{
    int i = blockIdx.x * blockDim.x + threadIdx.x;
    if (i >= NN) return;
    float acc = 0.f;
    int e0 = rp[i], e1 = rp[i + 1];
    int e = e0;
    for (; e + 4 <= e1; e += 4) {
        float t0 = ones_in ? 1.f : tin[ss[e]];
        float t1v = ones_in ? 1.f : tin[ss[e + 1]];
        float t2v = ones_in ? 1.f : tin[ss[e + 2]];
        float t3v = ones_in ? 1.f : tin[ss[e + 3]];
        acc += sw[e] * t0 + sw[e + 1] * t1v + sw[e + 2] * t2v + sw[e + 3] * t3v;
    }
    for (; e < e1; ++e) {
        float tv = ones_in ? 1.f : tin[ss[e]];
        acc += sw[e] * tv;
    }
    float pv = ones_prev ? 1.f : (tprev ? tprev[i] : 0.f);
    tout[i] = alpha * acc + beta * pv;
}

// colsum of Wh[l, g(0..1), k] -> scol[(l*2+g)*K + k][d]
__global__ __launch_bounds__(128) void colsum_kernel(
    const float* __restrict__ Wh, float* __restrict__ scol)
{
    int b = blockIdx.x;
    int k = b % KK;
    int g = (b / KK) % 2;
    int l = b / (2 * KK);
    int d = threadIdx.x;
    const float* Wp = Wh + ((size_t)((l * 3 + g) * KK + k)) * DD * DD;
    float s = 0.f;
    for (int r = 0; r < DD; ++r) s += Wp[r * DD + d];
    scol[((size_t)((l * 2 + g) * KK + k)) * DD + d] = s;
}

// ===================== weight convert: fp32 -> fp16, transposed + pre-swizzled ==
__global__ __launch_bounds__(256) void wconv_f16(
    const float* __restrict__ W, ushort* __restrict__ out, int mode)
{
    int t = blockIdx.x;
    int st = (mode == 0) ? t : ((t / KK) * 3 + 2) * KK + (t % KK);
    const float* Wp = W + (size_t)st * DD * DD;
    ushort* op = out + (size_t)t * DD * DD;
    for (int idx = threadIdx.x; idx < DD * DD; idx += 256) {
        int rb = idx >> 7, c = idx & 127;
        float w = Wp[c * DD + rb];          // transpose: [dout][din] from [din][dout]
        int byte = rb * 256 + (((c * 2) ^ ((rb & 7) << 4)));
        *(ushort*)((char*)op + byte) = f2h(w);
    }
}

// ===================== f32 (row-major) -> f16 4-panels =====================
__global__ __launch_bounds__(256) void f32_to_f16_panel(
    const float* __restrict__ in, ushort* __restrict__ out, int n8)
{
    int j = blockIdx.x * blockDim.x + threadIdx.x;
    if (j >= n8) return;
    int flat = j * 8;
    int i = flat >> 7;        // node
    int d0 = flat & 127;      // 0,8,...,120
    float4 a = *(const float4*)(in + (size_t)i * DD + d0);
    float4 b = *(const float4*)(in + (size_t)i * DD + d0 + 4);
    f16x8 o;
    o[0] = (_Float16)a.x; o[1] = (_Float16)a.y; o[2] = (_Float16)a.z; o[3] = (_Float16)a.w;
    o[4] = (_Float16)b.x; o[5] = (_Float16)b.y; o[6] = (_Float16)b.z; o[7] = (_Float16)b.w;
    *(f16x8*)(out + (size_t)(d0 >> 5) * PSZ32 + (size_t)i * 32 + (d0 & 31)) = o;
}

// ===================== dense fp16 propagation, 4x32-col panel layout ==========
__global__ __launch_bounds__(256) void prop_mat(
    const int* __restrict__ rp, const int* __restrict__ ss, const float* __restrict__ sw,
    const ushort* __restrict__ x, const ushort* __restrict__ prev,
    ushort* __restrict__ out, float alpha, float beta)
{
    const int p = blockIdx.x & 3;
    const int node = (blockIdx.x >> 2) * 64 + (threadIdx.x >> 2);
    if (node >= NN) return;
    const int lane8 = (threadIdx.x & 3) * 8;
    const ushort* xp = x + (size_t)p * PSZ32 + lane8;
    float acc[8];
#pragma unroll
    for (int j = 0; j < 8; ++j) acc[j] = 0.f;
    int e0 = rp[node], e1 = rp[node + 1];
    int e = e0;
    for (; e + 8 <= e1; e += 8) {
        int s0 = ss[e], s1 = ss[e + 1], s2 = ss[e + 2], s3 = ss[e + 3];
        int s4 = ss[e + 4], s5 = ss[e + 5], s6 = ss[e + 6], s7 = ss[e + 7];
        float w0 = sw[e], w1 = sw[e + 1], w2 = sw[e + 2], w3 = sw[e + 3];
        float w4 = sw[e + 4], w5 = sw[e + 5], w6 = sw[e + 6], w7 = sw[e + 7];
        f16x8 r0 = *(const f16x8*)(xp + (size_t)s0 * 32);
        f16x8 r1 = *(const f16x8*)(xp + (size_t)s1 * 32);
        f16x8 r2 = *(const f16x8*)(xp + (size_t)s2 * 32);
        f16x8 r3 = *(const f16x8*)(xp + (size_t)s3 * 32);
        f16x8 r4 = *(const f16x8*)(xp + (size_t)s4 * 32);
        f16x8 r5 = *(const f16x8*)(xp + (size_t)s5 * 32);
        f16x8 r6 = *(const f16x8*)(xp + (size_t)s6 * 32);
        f16x8 r7 = *(const f16x8*)(xp + (size_t)s7 * 32);
#pragma unroll
        for (int j = 0; j < 8; ++j)
            acc[j] += w0 * (float)r0[j] + w1 * (float)r1[j] + w2 * (float)r2[j] + w3 * (float)r3[j]
                    + w4 * (float)r4[j] + w5 * (float)r5[j] + w6 * (float)r6[j] + w7 * (float)r7[j];
    }
    for (; e + 4 <= e1; e += 4) {
        int s0 = ss[e], s1 = ss[e + 1], s2 = ss[e + 2], s3 = ss[e + 3];
        float w0 = sw[e], w1 = sw[e + 1], w2 = sw[e + 2], w3 = sw[e + 3];
        f16x8 r0 = *(const f16x8*)(xp + (size_t)s0 * 32);
        f16x8 r1 = *(const f16x8*)(xp + (size_t)s1 * 32);
        f16x8 r2 = *(const f16x8*)(xp + (size_t)s2 * 32);
        f16x8 r3 = *(const f16x8*)(xp + (size_t)s3 * 32);
#pragma unroll
        for (int j = 0; j < 8; ++j)
            acc[j] += w0 * (float)r0[j] + w1 * (float)r1[j] + w2 * (float)r2[j] + w3 * (float)r3[j];
    }
    for (; e < e1; ++e) {
        int s = ss[e];
        float w = sw[e];
        f16x8 r = *(const f16x8*)(xp + (size_t)s * 32);
#pragma unroll
        for (int j = 0; j < 8; ++j) acc[j] += w * (float)r[j];
    }
    f16x8 o;
    if (beta != 0.f && prev) {
        f16x8 pv = *(const f16x8*)(prev + (size_t)p * PSZ32 + (size_t)node * 32 + lane8);
#pragma unroll
        for (int j = 0; j < 8; ++j) o[j] = (_Float16)(alpha * acc[j] + beta * (float)pv[j]);
    } else {
#pragma unroll
        for (int j = 0; j < 8; ++j) o[j] = (_Float16)(alpha * acc[j]);
    }
    *(f16x8*)(out + (size_t)p * PSZ32 + (size_t)node * 32 + lane8) = o;
}

// ===================== shared MFMA gate core: 2-k-tile LDS staging ============
template<int NFR>
__device__ __forceinline__ void mm_gate(
    const ushort* __restrict__ const* Ts, const ushort* __restrict__ Wg,
    ushort* Bs, const int* rowg, const bool* ok,
    int tid, int lk, int lr, f32x4 acc[NFR][8])
{
#pragma unroll
    for (int fr = 0; fr < NFR; ++fr)
#pragma unroll
        for (int fc = 0; fc < 8; ++fc) acc[fr][fc] = (f32x4){0.f, 0.f, 0.f, 0.f};
#pragma unroll
    for (int rnd = 0; rnd < 3; ++rnd) {
        const int kb = rnd * 2;
        const int ntile = (rnd == 2) ? 1 : 2;
        __syncthreads();
#pragma unroll
        for (int t = 0; t < 2; ++t) {
            if (t < ntile) {
                const ushort* Bg = Wg + (size_t)(kb + t) * (DD * DD);
#pragma unroll
                for (int i = 0; i < 8; ++i) {
                    int off = i * 4096 + tid * 16;
                    uint4 v = *(const uint4*)((const char*)Bg + off);
                    *(uint4*)((char*)Bs + t * 32768 + off) = v;
                }
            }
        }
        __syncthreads();
#pragma unroll
        for (int t = 0; t < 2; ++t) {
            if (t < ntile) {
                const int k = kb + t;
                f16x8 a[NFR][4];
#pragma unroll
                for (int fr = 0; fr < NFR; ++fr) {
#pragma unroll
                    for (int ko = 0; ko < 4; ++ko) {
                        const ushort* ap = Ts[k] + (size_t)ko * PSZ32
                                         + (size_t)rowg[fr] * 32 + lk * 8;
                        if (ok[fr]) a[fr][ko] = *(const f16x8*)ap;
                        else a[fr][ko] = (f16x8){0, 0, 0, 0, 0, 0, 0, 0};
                    }
                }
                const char* base = (const char*)Bs + t * 32768;
#pragma unroll
                for (int ko = 0; ko < 4; ++ko) {
                    const int cb = ko * 64 + lk * 16;
#pragma unroll
                    for (int fc = 0; fc < 8; ++fc) {
                        int rb = fc * 16 + lr;
                        int byte = (rb * 256 + cb) ^ ((rb & 7) << 4);
                        f16x8 bfrag = *(const f16x8*)(base + byte);
#pragma unroll
                        for (int fr = 0; fr < NFR; ++fr)
                            acc[fr][fc] = __builtin_amdgcn_mfma_f32_16x16x32_f16(a[fr][ko], bfrag, acc[fr][fc], 0, 0, 0);
                    }
                }
            }
        }
    }
}

__device__ __forceinline__ int xcd_swz(int b, int nwg) {
    int xcd = b & 7, idx = b >> 3;
    int q = nwg >> 3, rr = nwg & 7;
    int start = (xcd < rr) ? xcd * (q + 1) : rr * (q + 1) + (xcd - rr) * q;
    return start + idx;
}

// ===================== fp16 MFMA Chebyshev matmul (parallel gates, 128-row) ===
__global__ __launch_bounds__(256) void cheb_mm_mfma(
    const ushort* __restrict__ T0, const ushort* __restrict__ T1,
    const ushort* __restrict__ T2, const ushort* __restrict__ T3,
    const ushort* __restrict__ T4,
    const ushort* __restrict__ Wt, int gate_stride,
    float* __restrict__ outbase, size_t out_stride, int ngates)
{
    __shared__ ushort Bs[DD * DD * 2];   // 64KB, 2 k-tile slots
    const int lin = xcd_swz(blockIdx.x, gridDim.x);
    const int tile = lin / ngates;
    const int g = lin - tile * ngates;

    const int tid = threadIdx.x;
    const int lane = tid & 63;
    const int wid = tid >> 6;
    const int lr = lane & 15;
    const int lk = lane >> 4;
    const int r0 = tile * 128;
    const ushort* Ts[5] = {T0, T1, T2, T3, T4};

    int rowg[2] = {r0 + wid * 32 + lr, r0 + wid * 32 + lr + 16};
    bool ok[2] = {rowg[0] < NN, rowg[1] < NN};

    f32x4 acc[2][8];
    mm_gate<2>(Ts, Wt + (size_t)g * gate_stride, Bs, rowg, ok, tid, lk, lr, acc);

    float* outp = outbase + (size_t)g * out_stride;
#pragma unroll
    for (int fr = 0; fr < 2; ++fr) {
#pragma unroll
        for (int j = 0; j < 4; ++j) {
            int grow = r0 + wid * 32 + fr * 16 + lk * 4 + j;
            if (grow < NN) {
#pragma unroll
                for (int fc = 0; fc < 8; ++fc) {
                    int col = fc * 16 + lr;
                    outp[(size_t)grow * DD + col] = acc[fr][fc][j];
                }
            }
        }
    }
}

// ===================== fused Wh-matmul + final GRU gate (64-row tiles) ========
__global__ __launch_bounds__(256) void cheb_mm_final(
    const ushort* __restrict__ T0, const ushort* __restrict__ T1,
    const ushort* __restrict__ T2, const ushort* __restrict__ T3,
    const ushort* __restrict__ T4,
    const ushort* __restrict__ Wt,
    const float* __restrict__ Xh, const float* __restrict__ Xz,
    const float* __restrict__ bx, const float* __restrict__ bh, int l,
    float* __restrict__ out, ushort* __restrict__ h16, int write_f32)
{
    __shared__ ushort Bs[DD * DD * 2];   // 64KB, 2 k-tile slots
    const int tile = xcd_swz(blockIdx.x, gridDim.x);
    const int tid = threadIdx.x;
    const int lane = tid & 63;
    const int wid = tid >> 6;
    const int lr = lane & 15;
    const int lk = lane >> 4;
    const int r0 = tile * 64;
    const ushort* Ts[5] = {T0, T1, T2, T3, T4};

    int rowg[1] = {r0 + wid * 16 + lr};
    bool ok[1] = {rowg[0] < NN};

    f32x4 acc[1][8];
    mm_gate<1>(Ts, Wt, Bs, rowg, ok, tid, lk, lr, acc);

    const float* b0 = bx + (size_t)(l * 3 + 2) * DD;
    const float* b1 = bh + (size_t)(l * 3 + 2) * DD;
#pragma unroll
    for (int j = 0; j < 4; ++j) {
        int grow = r0 + wid * 16 + lk * 4 + j;
        if (grow < NN) {
#pragma unroll
            for (int fc = 0; fc < 8; ++fc) {
                int d = fc * 16 + lr;
                size_t idx = (size_t)grow * DD + d;
                float pre = acc[0][fc][j] + Xh[idx] + b0[d] + b1[d];
                float ht = tanhf(pre);
                float z = Xz[idx];
                float hn = z + (1.f - z) * ht;
                float h = hn > 0.f ? hn : 0.f;
                if (write_f32) out[idx] = h;
                else h16[(size_t)(d >> 5) * PSZ32 + (size_t)grow * 32 + (d & 31)] = f2h(h);
            }
        }
    }
}

// ===================== gate kernel: Z,R from raw matmul results ===============
__global__ __launch_bounds__(256) void gate_zr_kernel(
    float* __restrict__ Xz, const float* __restrict__ Xr, ushort* __restrict__ Xr_f16,
    const float* __restrict__ tvec, const float* __restrict__ scol,
    const float* __restrict__ bx, const float* __restrict__ bh, int l)
{
    int idx = blockIdx.x * blockDim.x + threadIdx.x;
    if (idx >= NN * DD) return;
    int i = idx >> 7;
    int d = idx & 127;
    float t1 = tvec[i], t2 = tvec[NN + i], t3 = tvec[2 * NN + i], t4 = tvec[3 * NN + i];

    const float* s0 = scol + (size_t)((l * 2 + 0) * KK) * DD;
    float hz = s0[d] + t1 * s0[DD + d] + t2 * s0[2 * DD + d] + t3 * s0[3 * DD + d] + t4 * s0[4 * DD + d];
    float z = Xz[idx] + bx[(l * 3 + 0) * DD + d] + bh[(l * 3 + 0) * DD + d] + hz;
    Xz[idx] = 1.f / (1.f + expf(-z));

    const float* s1 = scol + (size_t)((l * 2 + 1) * KK) * DD;
    float hr = s1[d] + t1 * s1[DD + d] + t2 * s1[2 * DD + d] + t3 * s1[3 * DD + d] + t4 * s1[4 * DD + d];
    float r = Xr[idx] + bx[(l * 3 + 1) * DD + d] + bh[(l * 3 + 1) * DD + d] + hr;
    Xr_f16[(size_t)(d >> 5) * PSZ32 + (size_t)i * 32 + (d & 31)] = f2h(1.f / (1.f + expf(-r)));
}

// ===================== host orchestration =====================

extern "C" void kernel_launch(void* const* d_in, const int* in_sizes, int n_in,
                              void* d_out, int out_size, void* d_ws, size_t ws_size,
                              hipStream_t stream)
{
    const int*   ei  = (const int*)d_in[0];
    const float* ew  = (const float*)d_in[1];
    const float* emb = (const float*)d_in[2];
    const float* Wx  = (const float*)d_in[3];
    const float* bx  = (const float*)d_in[4];
    const float* Wh  = (const float*)d_in[5];
    const float* bh  = (const float*)d_in[6];
    float* out = (float*)d_out;

    const int* src = ei;
    const int* dst = ei + EE;

    char* ws = (char*)d_ws;
    size_t off = 0;
    auto alloc = [&](size_t nbytes) -> char* {
        char* p = ws + off;
        off = (off + nbytes + 255) & ~(size_t)255;
        return p;
    };
    float*  deg     = (float*)alloc((size_t)NN * 4);
    float*  dinv    = (float*)alloc((size_t)NN * 4);
    int*    hist    = (int*)alloc((size_t)(NN + 1) * 4);
    int*    row_ptr = (int*)alloc((size_t)(NN + 1) * 4);
    int*    fill    = (int*)alloc((size_t)(NN + 1) * 4);
    int*    bsum    = (int*)alloc((size_t)(SNB + 1) * 4);
    int*    src_srt = (int*)alloc((size_t)EE * 4);
    float*  w_srt   = (float*)alloc((size_t)EE * 4);
    float*  tvec    = (float*)alloc((size_t)4 * NN * 4);
    float*  scol    = (float*)alloc((size_t)LL * 2 * KK * DD * 4);
    float*  X       = (float*)alloc((size_t)3 * NN * DD * 4);    // Xz,Xr,Xh fp32
    ushort* Th      = (ushort*)alloc((size_t)4 * NN * DD * 2);   // T1..T4 f16 panels
    ushort* x_f16   = (ushort*)alloc((size_t)NN * DD * 2);       // panels
    ushort* Xr_f16  = (ushort*)alloc((size_t)NN * DD * 2);       // panels
    ushort* WxT     = (ushort*)alloc((size_t)LL * 3 * KK * DD * DD * 2);
    ushort* WhT2    = (ushort*)alloc((size_t)LL * KK * DD * DD * 2);
    (void)ws_size; (void)in_sizes; (void)n_in; (void)out_size;

    float* Xz = X;
    float* Xr = X + (size_t)NN * DD;
    float* Xh = X + (size_t)2 * NN * DD;
    ushort* T1 = Th;
    ushort* T2 = Th + (size_t)NN * DD;
    ushort* T3 = Th + (size_t)2 * NN * DD;
    ushort* T4 = Th + (size_t)3 * NN * DD;

    const int EG = (EE + 255) / 256;
    const int NG = (NN + 255) / 256;
    const int PG = ((NN + 63) / 64) * 4;       // 4-panel prop grid
    const int ELG = (NN * DD + 255) / 256;
    const int MMG = (NN + 127) / 128;
    const int MMG2 = (NN + 63) / 64;
    const int CVG = (NN * DD / 8 + 255) / 256;
    const int GATE_STRIDE = KK * DD * DD;  // ushorts per gate

    hipMemsetAsync(deg, 0, (size_t)NN * 4, stream);
    hipMemsetAsync(hist, 0, (size_t)(NN + 1) * 4, stream);

    edge_pass1<<<EG, 256, 0, stream>>>(src, dst, ew, deg, hist);
    dinv_kernel<<<NG, 256, 0, stream>>>(deg, dinv);
    scan_p1<<<SNB, SCB, 0, stream>>>(hist, bsum);
    scan_p2<<<1, 256, 0, stream>>>(bsum);
    scan_p3<<<SNB, SCB, 0, stream>>>(hist, bsum, row_ptr, fill);
    edge_scatter<<<EG, 256, 0, stream>>>(src, dst, ew, dinv, fill, src_srt, w_srt);

    // scalar Chebyshev vectors t1..t4 (t0 = ones, implicit)
    float* t1 = tvec;
    float* t2 = tvec + NN;
    float* t3 = tvec + 2 * NN;
    float* t4 = tvec + 3 * NN;
    propv_kernel<<<NG, 256, 0, stream>>>(row_ptr, src_srt, w_srt, nullptr, nullptr, t1, 1.f,  0.f, 1, 0);
    propv_kernel<<<NG, 256, 0, stream>>>(row_ptr, src_srt, w_srt, t1, nullptr,      t2, 2.f, -1.f, 0, 1);
    propv_kernel<<<NG, 256, 0, stream>>>(row_ptr, src_srt, w_srt, t2, t1,           t3, 2.f, -1.f, 0, 0);
    propv_kernel<<<NG, 256, 0, stream>>>(row_ptr, src_srt, w_srt, t3, t2,           t4, 2.f, -1.f, 0, 0);

    colsum_kernel<<<LL * 2 * KK, 128, 0, stream>>>(Wh, scol);

    // weights -> f16, transposed + pre-swizzled (LDS staging layout)
    wconv_f16<<<LL * 3 * KK, 256, 0, stream>>>(Wx, WxT, 0);
    wconv_f16<<<LL * KK, 256, 0, stream>>>(Wh, WhT2, 1);

    // emb -> f16 panels
    f32_to_f16_panel<<<CVG, 256, 0, stream>>>(emb, x_f16, NN * DD / 8);

    for (int l = 0; l < LL; ++l) {
        // Chebyshev basis of x (f16 panels, fp32 accumulate)
        prop_mat<<<PG, 256, 0, stream>>>(row_ptr, src_srt, w_srt, x_f16, nullptr, T1, 1.f,  0.f);
        prop_mat<<<PG, 256, 0, stream>>>(row_ptr, src_srt, w_srt, T1,    x_f16,   T2, 2.f, -1.f);
        prop_mat<<<PG, 256, 0, stream>>>(row_ptr, src_srt, w_srt, T2,    T1,      T3, 2.f, -1.f);
        prop_mat<<<PG, 256, 0, stream>>>(row_ptr, src_srt, w_srt, T3,    T2,      T4, 2.f, -1.f);

        // Xg = sum_k T_k @ Wx[l,g,k], g=0..2 (parallel gate blocks, XCD co-located)
        cheb_mm_mfma<<<MMG * 3, 256, 0, stream>>>(x_f16, T1, T2, T3, T4,
                                             WxT + (size_t)l * 3 * GATE_STRIDE, GATE_STRIDE,
                                             Xz, (size_t)NN * DD, 3);

        // Z, R (rank-K ones-side cheb + biases); Xz sigmoid in-place + Xr f16 panels
        gate_zr_kernel<<<ELG, 256, 0, stream>>>(Xz, Xr, Xr_f16, tvec, scol, bx, bh, l);

        // Chebyshev basis of R (H*R == R since H == ones)
        prop_mat<<<PG, 256, 0, stream>>>(row_ptr, src_srt, w_srt, Xr_f16, nullptr, T1, 1.f,  0.f);
        prop_mat<<<PG, 256, 0, stream>>>(row_ptr, src_srt, w_srt, T1,     Xr_f16,  T2, 2.f, -1.f);
        prop_mat<<<PG, 256, 0, stream>>>(row_ptr, src_srt, w_srt, T2,     T1,      T3, 2.f, -1.f);
        prop_mat<<<PG, 256, 0, stream>>>(row_ptr, src_srt, w_srt, T3,     T2,      T4, 2.f, -1.f);

        // fused: Xh + sum_k TR_k @ Wh[l,2,k] + final GRU gate (64-row tiles)
        cheb_mm_final<<<MMG2, 256, 0, stream>>>(Xr_f16, T1, T2, T3, T4,
                                               WhT2 + (size_t)l * GATE_STRIDE,
                                               Xh, Xz, bx, bh, l,
                                               out, x_f16, (l == LL - 1) ? 1 : 0);
    }
}

// Round 15
// 782.200 us; speedup vs baseline: 1.3858x; 1.0345x over previous
//
#include <hip/hip_runtime.h>
#include <math.h>

#define NN 50000
#define EE 500000
#define DD 128
#define KK 5
#define LL 2

// 4-panel layout for f16 N x D state: [4 panels][NN][32] (panel p = cols 32p..32p+31)
#define PSZ32 ((size_t)NN * 32)

// multi-block scan geometry
#define SCB 256
#define SNB ((NN + SCB - 1) / SCB)

typedef _Float16 f16x8 __attribute__((ext_vector_type(8)));
typedef float f32x4 __attribute__((ext_vector_type(4)));
typedef unsigned int u32x4 __attribute__((ext_vector_type(4)));

__device__ __forceinline__ ushort f2h(float x) {
    union { _Float16 h; ushort u; } v; v.h = (_Float16)x; return v.u;
}

// ===================== graph preprocessing =====================

__global__ __launch_bounds__(256) void edge_pass1(
    const int* __restrict__ src, const int* __restrict__ dst,
    const float* __restrict__ ew,
    float* __restrict__ deg, int* __restrict__ hist)
{
    int e = blockIdx.x * blockDim.x + threadIdx.x;
    if (e >= EE) return;
    atomicAdd(&deg[src[e]], ew[e]);
    atomicAdd(&hist[dst[e]], 1);
}

__global__ __launch_bounds__(256) void dinv_kernel(
    const float* __restrict__ deg, float* __restrict__ dinv)
{
    int i = blockIdx.x * blockDim.x + threadIdx.x;
    if (i >= NN) return;
    float d = deg[i];
    dinv[i] = (d > 0.f) ? (1.f / sqrtf(d)) : 0.f;
}

// ---- 3-pass coalesced multi-block scan ----
__global__ __launch_bounds__(SCB) void scan_p1(
    const int* __restrict__ hist, int* __restrict__ bsum)
{
    __shared__ int buf[SCB];
    int i = blockIdx.x * SCB + threadIdx.x;
    int v = (i < NN) ? hist[i] : 0;
    buf[threadIdx.x] = v;
    __syncthreads();
    for (int off = SCB / 2; off > 0; off >>= 1) {
        if (threadIdx.x < off) buf[threadIdx.x] += buf[threadIdx.x + off];
        __syncthreads();
    }
    if (threadIdx.x == 0) bsum[blockIdx.x] = buf[0];
}

__global__ __launch_bounds__(256) void scan_p2(
    int* __restrict__ bsum)   // in-place -> exclusive prefix
{
    __shared__ int buf[256];
    int t = threadIdx.x;
    int v = (t < SNB) ? bsum[t] : 0;
    buf[t] = v;
    __syncthreads();
    for (int off = 1; off < 256; off <<= 1) {
        int u = (t >= off) ? buf[t - off] : 0;
        __syncthreads();
        buf[t] += u;
        __syncthreads();
    }
    if (t < SNB) bsum[t] = buf[t] - v;   // exclusive
}

__global__ __launch_bounds__(SCB) void scan_p3(
    const int* __restrict__ hist, const int* __restrict__ bsum,
    int* __restrict__ row_ptr, int* __restrict__ fill)
{
    __shared__ int buf[SCB];
    int t = threadIdx.x;
    int i = blockIdx.x * SCB + t;
    int v = (i < NN) ? hist[i] : 0;
    buf[t] = v;
    __syncthreads();
    for (int off = 1; off < SCB; off <<= 1) {
        int u = (t >= off) ? buf[t - off] : 0;
        __syncthreads();
        buf[t] += u;
        __syncthreads();
    }
    int incl = buf[t] + bsum[blockIdx.x];
    if (i < NN) {
        row_ptr[i + 1] = incl;
        fill[i] = incl - v;
    }
    if (i == 0) row_ptr[0] = 0;
}

__global__ __launch_bounds__(256) void edge_scatter(
    const int* __restrict__ src, const int* __restrict__ dst,
    const float* __restrict__ ew, const float* __restrict__ dinv,
    int* __restrict__ fill,
    int* __restrict__ src_srt, float* __restrict__ w_srt)
{
    int e = blockIdx.x * blockDim.x + threadIdx.x;
    if (e >= EE) return;
    int s = src[e], t = dst[e];
    float w = -dinv[s] * ew[e] * dinv[t];
    int pos = atomicAdd(&fill[t], 1);
    src_srt[pos] = s;
    w_srt[pos] = w;
}

// ===================== scalar Chebyshev vectors (for H = ones) =====================
__global__ __launch_bounds__(256) void propv_kernel(
    const int* __restrict__ rp, const int* __restrict__ ss, const float* __restrict__ sw,
    const float* __restrict__ tin, const float* __restrict__ tprev, float* __restrict__ tout,
    float alpha, float beta, int ones_in, int ones_prev)
{
    int i = blockIdx.x * blockDim.x + threadIdx.x;
    if (i >= NN) return;
    float acc = 0.f;
    int e0 = rp[i], e1 = rp[i + 1];
    int e = e0;
    for (; e + 4 <= e1; e += 4) {
        float t0 = ones_in ? 1.f : tin[ss[e]];
        float t1v = ones_in ? 1.f : tin[ss[e + 1]];
        float t2v = ones_in ? 1.f : tin[ss[e + 2]];
        float t3v = ones_in ? 1.f : tin[ss[e + 3]];
        acc += sw[e] * t0 + sw[e + 1] * t1v + sw[e + 2] * t2v + sw[e + 3] * t3v;
    }
    for (; e < e1; ++e) {
        float tv = ones_in ? 1.f : tin[ss[e]];
        acc += sw[e] * tv;
    }
    float pv = ones_prev ? 1.f : (tprev ? tprev[i] : 0.f);
    tout[i] = alpha * acc + beta * pv;
}

// colsum of Wh[l, g(0..1), k] -> scol[(l*2+g)*K + k][d]
__global__ __launch_bounds__(128) void colsum_kernel(
    const float* __restrict__ Wh, float* __restrict__ scol)
{
    int b = blockIdx.x;
    int k = b % KK;
    int g = (b / KK) % 2;
    int l = b / (2 * KK);
    int d = threadIdx.x;
    const float* Wp = Wh + ((size_t)((l * 3 + g) * KK + k)) * DD * DD;
    float s = 0.f;
    for (int r = 0; r < DD; ++r) s += Wp[r * DD + d];
    scol[((size_t)((l * 2 + g) * KK + k)) * DD + d] = s;
}

// ===================== weight convert: fp32 -> fp16, transposed + pre-swizzled ==
__global__ __launch_bounds__(256) void wconv_f16(
    const float* __restrict__ W, ushort* __restrict__ out, int mode)
{
    int t = blockIdx.x;
    int st = (mode == 0) ? t : ((t / KK) * 3 + 2) * KK + (t % KK);
    const float* Wp = W + (size_t)st * DD * DD;
    ushort* op = out + (size_t)t * DD * DD;
    for (int idx = threadIdx.x; idx < DD * DD; idx += 256) {
        int rb = idx >> 7, c = idx & 127;
        float w = Wp[c * DD + rb];          // transpose: [dout][din] from [din][dout]
        int byte = rb * 256 + (((c * 2) ^ ((rb & 7) << 4)));
        *(ushort*)((char*)op + byte) = f2h(w);
    }
}

// ===================== f32 (row-major) -> f16 4-panels =====================
__global__ __launch_bounds__(256) void f32_to_f16_panel(
    const float* __restrict__ in, ushort* __restrict__ out, int n8)
{
    int j = blockIdx.x * blockDim.x + threadIdx.x;
    if (j >= n8) return;
    int flat = j * 8;
    int i = flat >> 7;        // node
    int d0 = flat & 127;      // 0,8,...,120
    float4 a = *(const float4*)(in + (size_t)i * DD + d0);
    float4 b = *(const float4*)(in + (size_t)i * DD + d0 + 4);
    f16x8 o;
    o[0] = (_Float16)a.x; o[1] = (_Float16)a.y; o[2] = (_Float16)a.z; o[3] = (_Float16)a.w;
    o[4] = (_Float16)b.x; o[5] = (_Float16)b.y; o[6] = (_Float16)b.z; o[7] = (_Float16)b.w;
    *(f16x8*)(out + (size_t)(d0 >> 5) * PSZ32 + (size_t)i * 32 + (d0 & 31)) = o;
}

// ===================== dense fp16 propagation, 4x32-col panel layout ==========
__global__ __launch_bounds__(256) void prop_mat(
    const int* __restrict__ rp, const int* __restrict__ ss, const float* __restrict__ sw,
    const ushort* __restrict__ x, const ushort* __restrict__ prev,
    ushort* __restrict__ out, float alpha, float beta)
{
    const int p = blockIdx.x & 3;
    const int node = (blockIdx.x >> 2) * 64 + (threadIdx.x >> 2);
    if (node >= NN) return;
    const int lane8 = (threadIdx.x & 3) * 8;
    const ushort* xp = x + (size_t)p * PSZ32 + lane8;
    float acc[8];
#pragma unroll
    for (int j = 0; j < 8; ++j) acc[j] = 0.f;
    int e0 = rp[node], e1 = rp[node + 1];
    int e = e0;
    for (; e + 8 <= e1; e += 8) {
        int s0 = ss[e], s1 = ss[e + 1], s2 = ss[e + 2], s3 = ss[e + 3];
        int s4 = ss[e + 4], s5 = ss[e + 5], s6 = ss[e + 6], s7 = ss[e + 7];
        float w0 = sw[e], w1 = sw[e + 1], w2 = sw[e + 2], w3 = sw[e + 3];
        float w4 = sw[e + 4], w5 = sw[e + 5], w6 = sw[e + 6], w7 = sw[e + 7];
        f16x8 r0 = *(const f16x8*)(xp + (size_t)s0 * 32);
        f16x8 r1 = *(const f16x8*)(xp + (size_t)s1 * 32);
        f16x8 r2 = *(const f16x8*)(xp + (size_t)s2 * 32);
        f16x8 r3 = *(const f16x8*)(xp + (size_t)s3 * 32);
        f16x8 r4 = *(const f16x8*)(xp + (size_t)s4 * 32);
        f16x8 r5 = *(const f16x8*)(xp + (size_t)s5 * 32);
        f16x8 r6 = *(const f16x8*)(xp + (size_t)s6 * 32);
        f16x8 r7 = *(const f16x8*)(xp + (size_t)s7 * 32);
#pragma unroll
        for (int j = 0; j < 8; ++j)
            acc[j] += w0 * (float)r0[j] + w1 * (float)r1[j] + w2 * (float)r2[j] + w3 * (float)r3[j]
                    + w4 * (float)r4[j] + w5 * (float)r5[j] + w6 * (float)r6[j] + w7 * (float)r7[j];
    }
    for (; e + 4 <= e1; e += 4) {
        int s0 = ss[e], s1 = ss[e + 1], s2 = ss[e + 2], s3 = ss[e + 3];
        float w0 = sw[e], w1 = sw[e + 1], w2 = sw[e + 2], w3 = sw[e + 3];
        f16x8 r0 = *(const f16x8*)(xp + (size_t)s0 * 32);
        f16x8 r1 = *(const f16x8*)(xp + (size_t)s1 * 32);
        f16x8 r2 = *(const f16x8*)(xp + (size_t)s2 * 32);
        f16x8 r3 = *(const f16x8*)(xp + (size_t)s3 * 32);
#pragma unroll
        for (int j = 0; j < 8; ++j)
            acc[j] += w0 * (float)r0[j] + w1 * (float)r1[j] + w2 * (float)r2[j] + w3 * (float)r3[j];
    }
    for (; e < e1; ++e) {
        int s = ss[e];
        float w = sw[e];
        f16x8 r = *(const f16x8*)(xp + (size_t)s * 32);
#pragma unroll
        for (int j = 0; j < 8; ++j) acc[j] += w * (float)r[j];
    }
    f16x8 o;
    if (beta != 0.f && prev) {
        f16x8 pv = *(const f16x8*)(prev + (size_t)p * PSZ32 + (size_t)node * 32 + lane8);
#pragma unroll
        for (int j = 0; j < 8; ++j) o[j] = (_Float16)(alpha * acc[j] + beta * (float)pv[j]);
    } else {
#pragma unroll
        for (int j = 0; j < 8; ++j) o[j] = (_Float16)(alpha * acc[j]);
    }
    *(f16x8*)(out + (size_t)p * PSZ32 + (size_t)node * 32 + lane8) = o;
}

// ===================== shared MFMA gate core: 2-k-tile LDS staging ============
// BT = block threads. 64KB LDS, 3 barrier-rounds for 5 k-tiles.
template<int NFR, int BT>
__device__ __forceinline__ void mm_gate(
    const ushort* __restrict__ const* Ts, const ushort* __restrict__ Wg,
    ushort* Bs, const int* rowg, const bool* ok,
    int tid, int lk, int lr, f32x4 acc[NFR][8])
{
#pragma unroll
    for (int fr = 0; fr < NFR; ++fr)
#pragma unroll
        for (int fc = 0; fc < 8; ++fc) acc[fr][fc] = (f32x4){0.f, 0.f, 0.f, 0.f};
#pragma unroll
    for (int rnd = 0; rnd < 3; ++rnd) {
        const int kb = rnd * 2;
        const int ntile = (rnd == 2) ? 1 : 2;
        __syncthreads();
#pragma unroll
        for (int t = 0; t < 2; ++t) {
            if (t < ntile) {
                const ushort* Bg = Wg + (size_t)(kb + t) * (DD * DD);
#pragma unroll
                for (int i = 0; i < 32768 / (BT * 16); ++i) {
                    int off = i * (BT * 16) + tid * 16;
                    uint4 v = *(const uint4*)((const char*)Bg + off);
                    *(uint4*)((char*)Bs + t * 32768 + off) = v;
                }
            }
        }
        __syncthreads();
#pragma unroll
        for (int t = 0; t < 2; ++t) {
            if (t < ntile) {
                const int k = kb + t;
                f16x8 a[NFR][4];
#pragma unroll
                for (int fr = 0; fr < NFR; ++fr) {
#pragma unroll
                    for (int ko = 0; ko < 4; ++ko) {
                        const ushort* ap = Ts[k] + (size_t)ko * PSZ32
                                         + (size_t)rowg[fr] * 32 + lk * 8;
                        if (ok[fr]) a[fr][ko] = *(const f16x8*)ap;
                        else a[fr][ko] = (f16x8){0, 0, 0, 0, 0, 0, 0, 0};
                    }
                }
                const char* base = (const char*)Bs + t * 32768;
#pragma unroll
                for (int ko = 0; ko < 4; ++ko) {
                    const int cb = ko * 64 + lk * 16;
#pragma unroll
                    for (int fc = 0; fc < 8; ++fc) {
                        int rb = fc * 16 + lr;
                        int byte = (rb * 256 + cb) ^ ((rb & 7) << 4);
                        f16x8 bfrag = *(const f16x8*)(base + byte);
#pragma unroll
                        for (int fr = 0; fr < NFR; ++fr)
                            acc[fr][fc] = __builtin_amdgcn_mfma_f32_16x16x32_f16(a[fr][ko], bfrag, acc[fr][fc], 0, 0, 0);
                    }
                }
            }
        }
    }
}

__device__ __forceinline__ int xcd_swz(int b, int nwg) {
    int xcd = b & 7, idx = b >> 3;
    int q = nwg >> 3, rr = nwg & 7;
    int start = (xcd < rr) ? xcd * (q + 1) : rr * (q + 1) + (xcd - rr) * q;
    return start + idx;
}

// ===================== fp16 MFMA Chebyshev matmul (parallel gates) ============
// 512 threads = 8 waves, 256-row tiles: each 32KB W stage feeds 8 waves.
__global__ __launch_bounds__(512) void cheb_mm_mfma(
    const ushort* __restrict__ T0, const ushort* __restrict__ T1,
    const ushort* __restrict__ T2, const ushort* __restrict__ T3,
    const ushort* __restrict__ T4,
    const ushort* __restrict__ Wt, int gate_stride,
    float* __restrict__ outbase, size_t out_stride, int ngates)
{
    __shared__ ushort Bs[DD * DD * 2];   // 64KB, 2 k-tile slots
    const int lin = xcd_swz(blockIdx.x, gridDim.x);
    const int tile = lin / ngates;
    const int g = lin - tile * ngates;

    const int tid = threadIdx.x;
    const int lane = tid & 63;
    const int wid = tid >> 6;          // 0..7
    const int lr = lane & 15;
    const int lk = lane >> 4;
    const int r0 = tile * 256;
    const ushort* Ts[5] = {T0, T1, T2, T3, T4};

    int rowg[2] = {r0 + wid * 32 + lr, r0 + wid * 32 + lr + 16};
    bool ok[2] = {rowg[0] < NN, rowg[1] < NN};

    f32x4 acc[2][8];
    mm_gate<2, 512>(Ts, Wt + (size_t)g * gate_stride, Bs, rowg, ok, tid, lk, lr, acc);

    float* outp = outbase + (size_t)g * out_stride;
#pragma unroll
    for (int fr = 0; fr < 2; ++fr) {
#pragma unroll
        for (int j = 0; j < 4; ++j) {
            int grow = r0 + wid * 32 + fr * 16 + lk * 4 + j;
            if (grow < NN) {
#pragma unroll
                for (int fc = 0; fc < 8; ++fc) {
                    int col = fc * 16 + lr;
                    outp[(size_t)grow * DD + col] = acc[fr][fc][j];
                }
            }
        }
    }
}

// ===================== fused Wh-matmul + final GRU gate =======================
// 512 threads = 8 waves, 128-row tiles.
__global__ __launch_bounds__(512) void cheb_mm_final(
    const ushort* __restrict__ T0, const ushort* __restrict__ T1,
    const ushort* __restrict__ T2, const ushort* __restrict__ T3,
    const ushort* __restrict__ T4,
    const ushort* __restrict__ Wt,
    const float* __restrict__ Xh, const float* __restrict__ Xz,
    const float* __restrict__ bx, const float* __restrict__ bh, int l,
    float* __restrict__ out, ushort* __restrict__ h16, int write_f32)
{
    __shared__ ushort Bs[DD * DD * 2];   // 64KB, 2 k-tile slots
    const int tile = xcd_swz(blockIdx.x, gridDim.x);
    const int tid = threadIdx.x;
    const int lane = tid & 63;
    const int wid = tid >> 6;          // 0..7
    const int lr = lane & 15;
    const int lk = lane >> 4;
    const int r0 = tile * 128;
    const ushort* Ts[5] = {T0, T1, T2, T3, T4};

    int rowg[1] = {r0 + wid * 16 + lr};
    bool ok[1] = {rowg[0] < NN};

    f32x4 acc[1][8];
    mm_gate<1, 512>(Ts, Wt, Bs, rowg, ok, tid, lk, lr, acc);

    const float* b0 = bx + (size_t)(l * 3 + 2) * DD;
    const float* b1 = bh + (size_t)(l * 3 + 2) * DD;
#pragma unroll
    for (int j = 0; j < 4; ++j) {
        int grow = r0 + wid * 16 + lk * 4 + j;
        if (grow < NN) {
#pragma unroll
            for (int fc = 0; fc < 8; ++fc) {
                int d = fc * 16 + lr;
                size_t idx = (size_t)grow * DD + d;
                float pre = acc[0][fc][j] + Xh[idx] + b0[d] + b1[d];
                float ht = tanhf(pre);
                float z = Xz[idx];
                float hn = z + (1.f - z) * ht;
                float h = hn > 0.f ? hn : 0.f;
                if (write_f32) out[idx] = h;
                else h16[(size_t)(d >> 5) * PSZ32 + (size_t)grow * 32 + (d & 31)] = f2h(h);
            }
        }
    }
}

// ===================== gate kernel: Z,R from raw matmul results ===============
__global__ __launch_bounds__(256) void gate_zr_kernel(
    float* __restrict__ Xz, const float* __restrict__ Xr, ushort* __restrict__ Xr_f16,
    const float* __restrict__ tvec, const float* __restrict__ scol,
    const float* __restrict__ bx, const float* __restrict__ bh, int l)
{
    int idx = blockIdx.x * blockDim.x + threadIdx.x;
    if (idx >= NN * DD) return;
    int i = idx >> 7;
    int d = idx & 127;
    float t1 = tvec[i], t2 = tvec[NN + i], t3 = tvec[2 * NN + i], t4 = tvec[3 * NN + i];

    const float* s0 = scol + (size_t)((l * 2 + 0) * KK) * DD;
    float hz = s0[d] + t1 * s0[DD + d] + t2 * s0[2 * DD + d] + t3 * s0[3 * DD + d] + t4 * s0[4 * DD + d];
    float z = Xz[idx] + bx[(l * 3 + 0) * DD + d] + bh[(l * 3 + 0) * DD + d] + hz;
    Xz[idx] = 1.f / (1.f + expf(-z));

    const float* s1 = scol + (size_t)((l * 2 + 1) * KK) * DD;
    float hr = s1[d] + t1 * s1[DD + d] + t2 * s1[2 * DD + d] + t3 * s1[3 * DD + d] + t4 * s1[4 * DD + d];
    float r = Xr[idx] + bx[(l * 3 + 1) * DD + d] + bh[(l * 3 + 1) * DD + d] + hr;
    Xr_f16[(size_t)(d >> 5) * PSZ32 + (size_t)i * 32 + (d & 31)] = f2h(1.f / (1.f + expf(-r)));
}

// ===================== host orchestration =====================

extern "C" void kernel_launch(void* const* d_in, const int* in_sizes, int n_in,
                              void* d_out, int out_size, void* d_ws, size_t ws_size,
                              hipStream_t stream)
{
    const int*   ei  = (const int*)d_in[0];
    const float* ew  = (const float*)d_in[1];
    const float* emb = (const float*)d_in[2];
    const float* Wx  = (const float*)d_in[3];
    const float* bx  = (const float*)d_in[4];
    const float* Wh  = (const float*)d_in[5];
    const float* bh  = (const float*)d_in[6];
    float* out = (float*)d_out;

    const int* src = ei;
    const int* dst = ei + EE;

    char* ws = (char*)d_ws;
    size_t off = 0;
    auto alloc = [&](size_t nbytes) -> char* {
        char* p = ws + off;
        off = (off + nbytes + 255) & ~(size_t)255;
        return p;
    };
    float*  deg     = (float*)alloc((size_t)NN * 4);
    float*  dinv    = (float*)alloc((size_t)NN * 4);
    int*    hist    = (int*)alloc((size_t)(NN + 1) * 4);
    int*    row_ptr = (int*)alloc((size_t)(NN + 1) * 4);
    int*    fill    = (int*)alloc((size_t)(NN + 1) * 4);
    int*    bsum    = (int*)alloc((size_t)(SNB + 1) * 4);
    int*    src_srt = (int*)alloc((size_t)EE * 4);
    float*  w_srt   = (float*)alloc((size_t)EE * 4);
    float*  tvec    = (float*)alloc((size_t)4 * NN * 4);
    float*  scol    = (float*)alloc((size_t)LL * 2 * KK * DD * 4);
    float*  X       = (float*)alloc((size_t)3 * NN * DD * 4);    // Xz,Xr,Xh fp32
    ushort* Th      = (ushort*)alloc((size_t)4 * NN * DD * 2);   // T1..T4 f16 panels
    ushort* x_f16   = (ushort*)alloc((size_t)NN * DD * 2);       // panels
    ushort* Xr_f16  = (ushort*)alloc((size_t)NN * DD * 2);       // panels
    ushort* WxT     = (ushort*)alloc((size_t)LL * 3 * KK * DD * DD * 2);
    ushort* WhT2    = (ushort*)alloc((size_t)LL * KK * DD * DD * 2);
    (void)ws_size; (void)in_sizes; (void)n_in; (void)out_size;

    float* Xz = X;
    float* Xr = X + (size_t)NN * DD;
    float* Xh = X + (size_t)2 * NN * DD;
    ushort* T1 = Th;
    ushort* T2 = Th + (size_t)NN * DD;
    ushort* T3 = Th + (size_t)2 * NN * DD;
    ushort* T4 = Th + (size_t)3 * NN * DD;

    const int EG = (EE + 255) / 256;
    const int NG = (NN + 255) / 256;
    const int PG = ((NN + 63) / 64) * 4;       // 4-panel prop grid
    const int ELG = (NN * DD + 255) / 256;
    const int MMG = (NN + 255) / 256;          // 256-row tiles (512-thr blocks)
    const int MMG2 = (NN + 127) / 128;         // 128-row tiles (512-thr blocks)
    const int CVG = (NN * DD / 8 + 255) / 256;
    const int GATE_STRIDE = KK * DD * DD;  // ushorts per gate

    hipMemsetAsync(deg, 0, (size_t)NN * 4, stream);
    hipMemsetAsync(hist, 0, (size_t)(NN + 1) * 4, stream);

    edge_pass1<<<EG, 256, 0, stream>>>(src, dst, ew, deg, hist);
    dinv_kernel<<<NG, 256, 0, stream>>>(deg, dinv);
    scan_p1<<<SNB, SCB, 0, stream>>>(hist, bsum);
    scan_p2<<<1, 256, 0, stream>>>(bsum);
    scan_p3<<<SNB, SCB, 0, stream>>>(hist, bsum, row_ptr, fill);
    edge_scatter<<<EG, 256, 0, stream>>>(src, dst, ew, dinv, fill, src_srt, w_srt);

    // scalar Chebyshev vectors t1..t4 (t0 = ones, implicit)
    float* t1 = tvec;
    float* t2 = tvec + NN;
    float* t3 = tvec + 2 * NN;
    float* t4 = tvec + 3 * NN;
    propv_kernel<<<NG, 256, 0, stream>>>(row_ptr, src_srt, w_srt, nullptr, nullptr, t1, 1.f,  0.f, 1, 0);
    propv_kernel<<<NG, 256, 0, stream>>>(row_ptr, src_srt, w_srt, t1, nullptr,      t2, 2.f, -1.f, 0, 1);
    propv_kernel<<<NG, 256, 0, stream>>>(row_ptr, src_srt, w_srt, t2, t1,           t3, 2.f, -1.f, 0, 0);
    propv_kernel<<<NG, 256, 0, stream>>>(row_ptr, src_srt, w_srt, t3, t2,           t4, 2.f, -1.f, 0, 0);

    colsum_kernel<<<LL * 2 * KK, 128, 0, stream>>>(Wh, scol);

    // weights -> f16, transposed + pre-swizzled (LDS staging layout)
    wconv_f16<<<LL * 3 * KK, 256, 0, stream>>>(Wx, WxT, 0);
    wconv_f16<<<LL * KK, 256, 0, stream>>>(Wh, WhT2, 1);

    // emb -> f16 panels
    f32_to_f16_panel<<<CVG, 256, 0, stream>>>(emb, x_f16, NN * DD / 8);

    for (int l = 0; l < LL; ++l) {
        // Chebyshev basis of x (f16 panels, fp32 accumulate)
        prop_mat<<<PG, 256, 0, stream>>>(row_ptr, src_srt, w_srt, x_f16, nullptr, T1, 1.f,  0.f);
        prop_mat<<<PG, 256, 0, stream>>>(row_ptr, src_srt, w_srt, T1,    x_f16,   T2, 2.f, -1.f);
        prop_mat<<<PG, 256, 0, stream>>>(row_ptr, src_srt, w_srt, T2,    T1,      T3, 2.f, -1.f);
        prop_mat<<<PG, 256, 0, stream>>>(row_ptr, src_srt, w_srt, T3,    T2,      T4, 2.f, -1.f);

        // Xg = sum_k T_k @ Wx[l,g,k], g=0..2 (parallel gate blocks, XCD co-located)
        cheb_mm_mfma<<<MMG * 3, 512, 0, stream>>>(x_f16, T1, T2, T3, T4,
                                             WxT + (size_t)l * 3 * GATE_STRIDE, GATE_STRIDE,
                                             Xz, (size_t)NN * DD, 3);

        // Z, R (rank-K ones-side cheb + biases); Xz sigmoid in-place + Xr f16 panels
        gate_zr_kernel<<<ELG, 256, 0, stream>>>(Xz, Xr, Xr_f16, tvec, scol, bx, bh, l);

        // Chebyshev basis of R (H*R == R since H == ones)
        prop_mat<<<PG, 256, 0, stream>>>(row_ptr, src_srt, w_srt, Xr_f16, nullptr, T1, 1.f,  0.f);
        prop_mat<<<PG, 256, 0, stream>>>(row_ptr, src_srt, w_srt, T1,     Xr_f16,  T2, 2.f, -1.f);
        prop_mat<<<PG, 256, 0, stream>>>(row_ptr, src_srt, w_srt, T2,     T1,      T3, 2.f, -1.f);
        prop_mat<<<PG, 256, 0, stream>>>(row_ptr, src_srt, w_srt, T3,     T2,      T4, 2.f, -1.f);

        // fused: Xh + sum_k TR_k @ Wh[l,2,k] + final GRU gate (128-row tiles)
        cheb_mm_final<<<MMG2, 512, 0, stream>>>(Xr_f16, T1, T2, T3, T4,
                                               WhT2 + (size_t)l * GATE_STRIDE,
                                               Xh, Xz, bx, bh, l,
                                               out, x_f16, (l == LL - 1) ? 1 : 0);
    }
}